// Round 2
// baseline (1057.102 us; speedup 1.0000x reference)
//
#include <hip/hip_runtime.h>
#include <cstdint>
#include <cstddef>

// ---------------- dims ----------------
#define BATCH 2
#define MQ 12544          // B * TQ * NQ
#define ROWS_Q 6272
#define MK 4096           // B * T*H*W
#define ROWS_K 2048
#define HID 512
#define NH 4
#define HD 128
#define EMB 1024
#define DQ 896
#define FF 1024
#define OUTD 896

typedef __bf16 bf16;
typedef unsigned int u32;
typedef bf16 bf16x8 __attribute__((ext_vector_type(8)));
typedef bf16 bf16x4 __attribute__((ext_vector_type(4)));
typedef float f32x4 __attribute__((ext_vector_type(4)));

enum { OP_BIAS = 0, OP_GELU = 1, OP_RES = 2 };

__device__ __forceinline__ float gelu_tanh(float x) {
    float x3 = x * x * x;
    return 0.5f * x * (1.0f + tanhf(0.7978845608028654f * (x + 0.044715f * x3)));
}

__device__ __forceinline__ void gld16(const bf16* g, bf16* l) {
    __builtin_amdgcn_global_load_lds(
        (const __attribute__((address_space(1))) unsigned int*)g,
        (__attribute__((address_space(3))) unsigned int*)l, 16, 0, 0);
}

__device__ __forceinline__ u32 pack_bf16(float a, float b) {
    union { bf16 h[2]; u32 w; } u;
    u.h[0] = (bf16)a; u.h[1] = (bf16)b;
    return u.w;
}

// ---------------------------------------------------------------------------
// bf16 MFMA GEMM, 128x128 tile (m97 structure). For N>=1024-ish shapes.
// ---------------------------------------------------------------------------
template <int OP, bool WF32, bool WB16>
__global__ __launch_bounds__(256) void mgemm(
    const bf16* __restrict__ A, const bf16* __restrict__ Bt,
    const float* __restrict__ bias, const float* __restrict__ res,
    float* __restrict__ Cf, bf16* __restrict__ Cb, int M, int N, int K)
{
    __shared__ __align__(16) bf16 As[128 * 32];
    __shared__ __align__(16) bf16 Bs[128 * 32];
    const int tid  = threadIdx.x;
    const int m0   = blockIdx.y * 128;
    const int n0   = blockIdx.x * 128;
    const int wave = tid >> 6, lane = tid & 63;
    const int wm = (wave >> 1) * 64, wn = (wave & 1) * 64;

    f32x4 acc[4][4] = {};

    const int srow = tid >> 2;
    const int scol = (tid & 3) * 8;
    const bf16* Ag = A  + (size_t)(m0 + srow) * K + scol;
    const bf16* Bg = Bt + (size_t)(n0 + srow) * K + scol;
    bf16* Al = &As[tid * 8];
    bf16* Bl = &Bs[tid * 8];
    const size_t half = (size_t)64 * K;

    const int fr = lane & 15;
    const int kq = (lane >> 4) * 8;
    const bf16* pa = &As[(wm + fr) * 32 + kq];
    const bf16* pb = &Bs[(wn + fr) * 32 + kq];

    for (int k0 = 0; k0 < K; k0 += 32) {
        gld16(Ag + k0,        Al);
        gld16(Ag + k0 + half, Al + 64 * 32);
        gld16(Bg + k0,        Bl);
        gld16(Bg + k0 + half, Bl + 64 * 32);
        __syncthreads();

        bf16x8 af[4], bfr[4];
        #pragma unroll
        for (int i = 0; i < 4; ++i) af[i]  = *(const bf16x8*)(pa + i * 16 * 32);
        #pragma unroll
        for (int j = 0; j < 4; ++j) bfr[j] = *(const bf16x8*)(pb + j * 16 * 32);
        #pragma unroll
        for (int i = 0; i < 4; ++i)
            #pragma unroll
            for (int j = 0; j < 4; ++j)
                acc[i][j] = __builtin_amdgcn_mfma_f32_16x16x32_bf16(
                    af[i], bfr[j], acc[i][j], 0, 0, 0);
        __syncthreads();
    }

    const int colb = n0 + wn + (lane & 15);
    const int rowb = m0 + wm + (lane >> 4) * 4;
    #pragma unroll
    for (int i = 0; i < 4; ++i) {
        #pragma unroll
        for (int j = 0; j < 4; ++j) {
            const int c = colb + j * 16;
            const float bj = bias[c];
            #pragma unroll
            for (int r = 0; r < 4; ++r) {
                const int m = rowb + i * 16 + r;
                float v = acc[i][j][r] + bj;
                if (OP == OP_GELU) v = gelu_tanh(v);
                if (OP == OP_RES)  v += res[(size_t)m * N + c];
                if (WF32) Cf[(size_t)m * N + c] = v;
                if (WB16) Cb[(size_t)m * N + c] = (bf16)v;
            }
        }
    }
}

// ---------------------------------------------------------------------------
// bf16 MFMA GEMM, 64x128 tile: doubles grid for occupancy-starved shapes.
// 4 waves as 2(m)x2(n); each wave 32m x 64n (acc 2x4). LDS 12 KB.
// ---------------------------------------------------------------------------
template <int OP, bool WF32, bool WB16>
__global__ __launch_bounds__(256) void mgemm64(
    const bf16* __restrict__ A, const bf16* __restrict__ Bt,
    const float* __restrict__ bias, const float* __restrict__ res,
    float* __restrict__ Cf, bf16* __restrict__ Cb, int M, int N, int K)
{
    __shared__ __align__(16) bf16 As[64 * 32];
    __shared__ __align__(16) bf16 Bs[128 * 32];
    const int tid  = threadIdx.x;
    const int m0   = blockIdx.y * 64;
    const int n0   = blockIdx.x * 128;
    const int wave = tid >> 6, lane = tid & 63;
    const int wm = (wave >> 1) * 32, wn = (wave & 1) * 64;

    f32x4 acc[2][4] = {};

    const int srow = tid >> 2;
    const int scol = (tid & 3) * 8;
    const bf16* Ag = A  + (size_t)(m0 + srow) * K + scol;
    const bf16* Bg = Bt + (size_t)(n0 + srow) * K + scol;
    bf16* Al = &As[tid * 8];
    bf16* Bl = &Bs[tid * 8];
    const size_t half = (size_t)64 * K;

    const int fr = lane & 15;
    const int kq = (lane >> 4) * 8;
    const bf16* pa = &As[(wm + fr) * 32 + kq];
    const bf16* pb = &Bs[(wn + fr) * 32 + kq];

    for (int k0 = 0; k0 < K; k0 += 32) {
        gld16(Ag + k0,        Al);
        gld16(Bg + k0,        Bl);
        gld16(Bg + k0 + half, Bl + 64 * 32);
        __syncthreads();

        bf16x8 af[2], bfr[4];
        #pragma unroll
        for (int i = 0; i < 2; ++i) af[i]  = *(const bf16x8*)(pa + i * 16 * 32);
        #pragma unroll
        for (int j = 0; j < 4; ++j) bfr[j] = *(const bf16x8*)(pb + j * 16 * 32);
        #pragma unroll
        for (int i = 0; i < 2; ++i)
            #pragma unroll
            for (int j = 0; j < 4; ++j)
                acc[i][j] = __builtin_amdgcn_mfma_f32_16x16x32_bf16(
                    af[i], bfr[j], acc[i][j], 0, 0, 0);
        __syncthreads();
    }

    const int colb = n0 + wn + (lane & 15);
    const int rowb = m0 + wm + (lane >> 4) * 4;
    #pragma unroll
    for (int i = 0; i < 2; ++i) {
        #pragma unroll
        for (int j = 0; j < 4; ++j) {
            const int c = colb + j * 16;
            const float bj = bias[c];
            #pragma unroll
            for (int r = 0; r < 4; ++r) {
                const int m = rowb + i * 16 + r;
                float v = acc[i][j][r] + bj;
                if (OP == OP_GELU) v = gelu_tanh(v);
                if (OP == OP_RES)  v += res[(size_t)m * N + c];
                if (WF32) Cf[(size_t)m * N + c] = v;
                if (WB16) Cb[(size_t)m * N + c] = (bf16)v;
            }
        }
    }
}

// ---------------------------------------------------------------------------
// All 9 weight transposes (fp32 KxN -> bf16 NxK) in ONE launch.
// ---------------------------------------------------------------------------
struct TDesc { const float* src; bf16* dst; int K; int N; int tile0; };
struct TDescs { TDesc d[9]; };

__global__ __launch_bounds__(256) void transpose_all(TDescs td)
{
    __shared__ float t[32][33];
    const int blk = blockIdx.x;
    int i = 0;
    #pragma unroll
    for (int j = 1; j < 9; ++j) if (blk >= td.d[j].tile0) i = j;
    const float* src = td.d[i].src;
    bf16* dst = td.d[i].dst;
    const int K = td.d[i].K, N = td.d[i].N;
    const int local = blk - td.d[i].tile0;
    const int ntx = N >> 5;
    const int bx = local % ntx, by = local / ntx;
    const int x = threadIdx.x & 31, y = threadIdx.x >> 5;
    #pragma unroll
    for (int p = 0; p < 32; p += 8)
        t[y + p][x] = src[(size_t)(by * 32 + y + p) * N + bx * 32 + x];
    __syncthreads();
    #pragma unroll
    for (int p = 0; p < 32; p += 8)
        dst[(size_t)(bx * 32 + y + p) * K + by * 32 + x] = (bf16)t[x][y + p];
}

// fp32 -> bf16 elementwise
__global__ __launch_bounds__(256) void cvt_kernel(
    const float* __restrict__ in, bf16* __restrict__ out, int n4)
{
    int i = blockIdx.x * 256 + threadIdx.x;
    if (i >= n4) return;
    float4 v = ((const float4*)in)[i];
    out[4 * i + 0] = (bf16)v.x;
    out[4 * i + 1] = (bf16)v.y;
    out[4 * i + 2] = (bf16)v.z;
    out[4 * i + 3] = (bf16)v.w;
}

// kv = x @ Wm + bm  (K=4), bf16 out.
__global__ __launch_bounds__(256) void kv_kernel(
    const float* __restrict__ x, const float* __restrict__ Wm,
    const float* __restrict__ bm, bf16* __restrict__ kv)
{
    int idx = blockIdx.x * 256 + threadIdx.x;
    int r = idx >> 10, n = idx & 1023;
    float4 xv = *(const float4*)(x + (size_t)r * 4);
    float v = bm[n] + xv.x * Wm[n] + xv.y * Wm[1024 + n]
                    + xv.z * Wm[2048 + n] + xv.w * Wm[3072 + n];
    kv[idx] = (bf16)v;
}

// 3D RoPE: bf16 in (row stride istr, col offset icoff) -> bf16 out (rows x 512).
__global__ __launch_bounds__(256) void rope_b_kernel(
    const bf16* __restrict__ in, bf16* __restrict__ out,
    int tok, int gdiv, int wdiv, int total, float sc, int istr, int icoff)
{
    int idx = blockIdx.x * 256 + threadIdx.x;
    if (idx >= total) return;
    int row = idx >> 7;
    int r2 = idx & 127;
    int h = r2 >> 5;
    int j2 = r2 & 31;
    int j = 2 * j2;
    int n = row % tok;
    int t = n / gdiv;
    int g = n % gdiv;
    int gh = g / wdiv;
    int gw = g % wdiv;
    float pa = (j < 22) ? (float)t : (j < 43) ? (float)gh : (float)gw;
    int j1 = j + 1;
    float pb = (j1 < 22) ? (float)t : (j1 < 43) ? (float)gh : (float)gw;
    float fra = pa * exp2f(-(float)j  * 0.20762050593045954f);
    float frb = pb * exp2f(-(float)j1 * 0.20762050593045954f);
    float ca = cosf(fra), sa = sinf(fra);
    float cb = cosf(frb), sb = sinf(frb);
    size_t ibase = (size_t)row * istr + icoff + (size_t)h * 128 + j;
    size_t obase = (size_t)row * 512 + (size_t)h * 128 + j;
    union { u32 w; bf16 e[2]; } ua, ub;
    ua.w = *(const u32*)(in + ibase);
    ub.w = *(const u32*)(in + ibase + 64);
    float x1a = (float)ua.e[0], x1b = (float)ua.e[1];
    float x2a = (float)ub.e[0], x2b = (float)ub.e[1];
    *(u32*)(out + obase)      = pack_bf16((x1a * ca - x2a * sa) * sc,
                                          (x1b * cb - x2b * sb) * sc);
    *(u32*)(out + obase + 64) = pack_bf16((x2a * ca + x1a * sa) * sc,
                                          (x2b * cb + x1b * sb) * sc);
}

// Coalesced V transpose: kv16[t][512 + h*128 + d] -> Vt[b][h][d][2048]
__global__ __launch_bounds__(256) void vt_tiled(
    const bf16* __restrict__ kv16, bf16* __restrict__ vt)
{
    __shared__ bf16 t[64][72];
    const int tt = blockIdx.x * 64;
    const int d0 = blockIdx.y * 64;
    const int bh = blockIdx.z;
    const int b = bh >> 2, h = bh & 3;
    const int rr = threadIdx.x >> 4;
    const int cc = (threadIdx.x & 15) * 4;
    #pragma unroll
    for (int p = 0; p < 4; ++p) {
        int r = rr + p * 16;
        *(bf16x4*)&t[r][cc] = *(const bf16x4*)
            (kv16 + (size_t)(b * ROWS_K + tt + r) * 1024 + 512 + h * 128 + d0 + cc);
    }
    __syncthreads();
    #pragma unroll
    for (int p = 0; p < 4; ++p) {
        int r = rr + p * 16;   // d-local
        bf16x4 v;
        v[0] = t[cc + 0][r]; v[1] = t[cc + 1][r];
        v[2] = t[cc + 2][r]; v[3] = t[cc + 3][r];
        *(bf16x4*)(vt + (size_t)bh * HD * ROWS_K + (size_t)(d0 + r) * ROWS_K + tt + cc) = v;
    }
}

// LayerNorm in-place on (rows x 512) + bf16 copy.
__global__ __launch_bounds__(256) void ln_kernel(
    float* __restrict__ xb, const float* __restrict__ g,
    const float* __restrict__ be, bf16* __restrict__ out16)
{
    int wave = threadIdx.x >> 6, lane = threadIdx.x & 63;
    size_t row = (size_t)blockIdx.x * 4 + wave;
    float* xp = xb + row * 512;
    float4 a = ((const float4*)xp)[lane];
    float4 b = ((const float4*)xp)[lane + 64];
    float s  = a.x + a.y + a.z + a.w + b.x + b.y + b.z + b.w;
    float sq = a.x*a.x + a.y*a.y + a.z*a.z + a.w*a.w
             + b.x*b.x + b.y*b.y + b.z*b.z + b.w*b.w;
    #pragma unroll
    for (int off = 32; off; off >>= 1) {
        s  += __shfl_xor(s, off);
        sq += __shfl_xor(sq, off);
    }
    float mean = s * (1.0f / 512.0f);
    float var  = sq * (1.0f / 512.0f) - mean * mean;
    float rstd = rsqrtf(var + 1e-5f);
    float4 gv1 = ((const float4*)g)[lane],  gv2 = ((const float4*)g)[lane + 64];
    float4 bv1 = ((const float4*)be)[lane], bv2 = ((const float4*)be)[lane + 64];
    a.x = (a.x - mean) * rstd * gv1.x + bv1.x;
    a.y = (a.y - mean) * rstd * gv1.y + bv1.y;
    a.z = (a.z - mean) * rstd * gv1.z + bv1.z;
    a.w = (a.w - mean) * rstd * gv1.w + bv1.w;
    b.x = (b.x - mean) * rstd * gv2.x + bv2.x;
    b.y = (b.y - mean) * rstd * gv2.y + bv2.y;
    b.z = (b.z - mean) * rstd * gv2.z + bv2.z;
    b.w = (b.w - mean) * rstd * gv2.w + bv2.w;
    ((float4*)xp)[lane]      = a;
    ((float4*)xp)[lane + 64] = b;
    bf16* op = out16 + row * 512;
    *(u32*)(op + lane * 4)       = pack_bf16(a.x, a.y);
    *(u32*)(op + lane * 4 + 2)   = pack_bf16(a.z, a.w);
    *(u32*)(op + 256 + lane * 4)     = pack_bf16(b.x, b.y);
    *(u32*)(op + 256 + lane * 4 + 2) = pack_bf16(b.z, b.w);
}

// ---------------------------------------------------------------------------
// MFMA flash attention (bf16, fp32 accum).
//   Round-2: 256 threads / 4 waves, 64 queries per block (16 per wave),
//   grid 784 (2b x 4h x 98 qtiles) -> ~3 blocks/CU resident (12 waves/CU),
//   vs round-0's 392-block/4.5-wave starvation. launch_bounds(256,2) keeps
//   the VGPR cap at 256 (round-1's (512,4) cap of 128 caused a spill
//   collapse to 48 VGPRs and a 4.5x regression).
//   LDS strides 6 mod 32 dwords (K:140, V:76, O:140): ds_read/write uniform
//   across banks (round-1 verified: conflicts 11.4M -> 4.1M).
//   Exact defer-rescale: skip O/l rescale when running max did not grow.
// LDS: Ksh 64x140x2 = 17920, Vsh 128x76x2 = 19456 -> 37376 B (4 blocks/CU).
// ---------------------------------------------------------------------------
#define KS 140
#define VS 76
#define OS 140

__global__ __launch_bounds__(256, 2) void mattn_kernel(
    const bf16* __restrict__ qs, const bf16* __restrict__ ks,
    const bf16* __restrict__ vt, bf16* __restrict__ outb)
{
    __shared__ __align__(16) char smem[37376];
    bf16* Ksh = (bf16*)smem;            // [64][KS]
    bf16* Vsh = (bf16*)(smem + 17920);  // [128][VS]

    const int tid = threadIdx.x;
    const int wave = tid >> 6, lane = tid & 63;
    const int quad = lane >> 4, c = lane & 15;
    const int bid = blockIdx.x;
    const int qt = bid % 98;
    const int h  = (bid / 98) & 3;
    const int b  = bid / 392;

    const int q0 = qt * 64 + wave * 16;
    const bf16* qg = qs + (size_t)(b * ROWS_Q + q0) * HID + h * HD;
    const bf16* kg = ks + (size_t)(b * ROWS_K) * HID + h * HD;
    const bf16* vg = vt + (size_t)(b * NH + h) * HD * ROWS_K;

    // Q fragments: lane (quad,c) holds q-col c, d-chunk s*32 + quad*8
    bf16x8 qf[4];
    #pragma unroll
    for (int s = 0; s < 4; ++s)
        qf[s] = *(const bf16x8*)(qg + (size_t)c * HID + s * 32 + quad * 8);

    f32x4 o[8] = {};
    float m_i = -1e30f, l_i = 0.0f;

    // staging (256 threads): K 64x128 (4 b128/thread), V 128x64 (4 b128/thread)
    const int st_t = tid >> 2;
    const int st_d = (tid & 3) * 32;
    const int sv_d = tid >> 1;
    const int sv_t = (tid & 1) * 32;

    for (int kt = 0; kt < 32; ++kt) {
        __syncthreads();
        {
            const bf16* src = kg + (size_t)(kt * 64 + st_t) * HID + st_d;
            bf16* dst = Ksh + st_t * KS + st_d;
            #pragma unroll
            for (int i = 0; i < 4; ++i)
                *(bf16x8*)(dst + i * 8) = *(const bf16x8*)(src + i * 8);
        }
        {
            const bf16* src = vg + (size_t)sv_d * ROWS_K + kt * 64 + sv_t;
            bf16* dst = Vsh + sv_d * VS + sv_t;
            #pragma unroll
            for (int i = 0; i < 4; ++i)
                *(bf16x8*)(dst + i * 8) = *(const bf16x8*)(src + i * 8);
        }
        __syncthreads();

        // QK^T: s[mi][r] = score(k = mi*16 + quad*4 + r, q = c)
        f32x4 s[4] = {};
        #pragma unroll
        for (int ksi = 0; ksi < 4; ++ksi) {
            bf16x8 kf[4];
            #pragma unroll
            for (int mi = 0; mi < 4; ++mi)
                kf[mi] = *(const bf16x8*)(Ksh + (mi * 16 + c) * KS + ksi * 32 + quad * 8);
            #pragma unroll
            for (int mi = 0; mi < 4; ++mi)
                s[mi] = __builtin_amdgcn_mfma_f32_16x16x32_bf16(
                    kf[mi], qf[ksi], s[mi], 0, 0, 0);
        }

        // online softmax (over k: mi, quad, r), per q = c
        float mx = -1e30f;
        #pragma unroll
        for (int mi = 0; mi < 4; ++mi)
            #pragma unroll
            for (int r = 0; r < 4; ++r) mx = fmaxf(mx, s[mi][r]);
        mx = fmaxf(mx, __shfl_xor(mx, 16));
        mx = fmaxf(mx, __shfl_xor(mx, 32));
        if (!__all(mx <= m_i)) {   // exact skip: alpha == 1 when max unchanged
            float mn = fmaxf(m_i, mx);
            float alpha = __expf(m_i - mn);
            m_i = mn;
            l_i *= alpha;
            #pragma unroll
            for (int md = 0; md < 8; ++md) {
                o[md][0] *= alpha; o[md][1] *= alpha;
                o[md][2] *= alpha; o[md][3] *= alpha;
            }
        }
        float sm = 0.0f;
        #pragma unroll
        for (int mi = 0; mi < 4; ++mi)
            #pragma unroll
            for (int r = 0; r < 4; ++r) {
                float p = __expf(s[mi][r] - m_i);
                s[mi][r] = p;
                sm += p;
            }
        sm += __shfl_xor(sm, 16);
        sm += __shfl_xor(sm, 32);
        l_i += sm;

        // repack P (rows=k, cols=q) into PV B-operand fragments
        u32 pk[4][2];
        #pragma unroll
        for (int mi = 0; mi < 4; ++mi) {
            pk[mi][0] = pack_bf16(s[mi][0], s[mi][1]);
            pk[mi][1] = pack_bf16(s[mi][2], s[mi][3]);
        }
        bf16x8 pf[2];
        #pragma unroll
        for (int kst = 0; kst < 2; ++kst) {
            union { bf16x8 v8; u32 d[4]; } u;
            #pragma unroll
            for (int dw = 0; dw < 4; ++dw) {
                int srcl = ((quad & 1) * 2 + (dw >> 1)) * 16 + c;
                u32 lo = (u32)__shfl((int)pk[2 * kst][dw & 1], srcl);
                u32 hi = (u32)__shfl((int)pk[2 * kst + 1][dw & 1], srcl);
                u.d[dw] = (quad >= 2) ? hi : lo;
            }
            pf[kst] = u.v8;
        }

        // PV: o[md][r] = O(q=c, d = md*16 + quad*4 + r)
        #pragma unroll
        for (int kst = 0; kst < 2; ++kst)
            #pragma unroll
            for (int md = 0; md < 8; ++md) {
                bf16x8 vf = *(const bf16x8*)(Vsh + (md * 16 + c) * VS + kst * 32 + quad * 8);
                o[md] = __builtin_amdgcn_mfma_f32_16x16x32_bf16(
                    vf, pf[kst], o[md], 0, 0, 0);
            }
    }

    __syncthreads();
    bf16* Osh = (bf16*)smem + wave * (16 * OS);
    float inv = 1.0f / l_i;
    #pragma unroll
    for (int md = 0; md < 8; ++md)
        #pragma unroll
        for (int hh = 0; hh < 2; ++hh) {
            u32 w = pack_bf16(o[md][2 * hh] * inv, o[md][2 * hh + 1] * inv);
            int d = md * 16 + quad * 4 + 2 * hh;
            *(u32*)(Osh + c * OS + d) = w;
        }
    __syncthreads();
    bf16* og = outb + (size_t)(b * ROWS_Q + qt * 64) * HID + h * HD;
    #pragma unroll
    for (int i = 0; i < 4; ++i) {
        int idx = i * 256 + tid;       // 0..1023 -> 64 rows x 16 chunks
        int qq = idx >> 4;
        int ch = idx & 15;
        bf16x8 vv = *(const bf16x8*)((bf16*)smem + (qq >> 4) * (16 * OS) + (qq & 15) * OS + ch * 8);
        *(bf16x8*)(og + (size_t)qq * HID + ch * 8) = vv;
    }
}

extern "C" void kernel_launch(void* const* d_in, const int* in_sizes, int n_in,
                              void* d_out, int out_size, void* d_ws, size_t ws_size,
                              hipStream_t stream)
{
    const float* x     = (const float*)d_in[0];
    const float* slow  = (const float*)d_in[1];
    const float* Wq_in = (const float*)d_in[3];
    const float* bq_in = (const float*)d_in[4];
    const float* Wm    = (const float*)d_in[5];
    const float* bm    = (const float*)d_in[6];
    const float* Wq    = (const float*)d_in[7];
    const float* bq    = (const float*)d_in[8];
    const float* Wk    = (const float*)d_in[9];
    const float* bk    = (const float*)d_in[10];
    const float* Wv    = (const float*)d_in[11];
    const float* bv    = (const float*)d_in[12];
    const float* Wo    = (const float*)d_in[13];
    const float* bo    = (const float*)d_in[14];
    const float* g1    = (const float*)d_in[15];
    const float* be1   = (const float*)d_in[16];
    const float* W1    = (const float*)d_in[17];
    const float* b1    = (const float*)d_in[18];
    const float* W2    = (const float*)d_in[19];
    const float* b2    = (const float*)d_in[20];
    const float* g2    = (const float*)d_in[21];
    const float* be2   = (const float*)d_in[22];
    const float* M1    = (const float*)d_in[23];
    const float* bm1   = (const float*)d_in[24];
    const float* M2    = (const float*)d_in[25];
    const float* bm2   = (const float*)d_in[26];
    float* out = (float*)d_out;

    // ---- workspace layout ----
    float* q_in_f = (float*)d_ws;                         // MQ*512 f32
    float* ob     = q_in_f + (size_t)MQ * HID;            // MQ*512 f32
    float* bkv    = ob + (size_t)MQ * HID;                // 1024 f32
    bf16* shared_b = (bf16*)(bkv + 1024);                 // MQ*1024 (slow_b/attn_b/ff1_b/m1_b)
    bf16* q_in_b = shared_b + (size_t)MQ * FF;            // MQ*512
    bf16* kv_b   = q_in_b + (size_t)MQ * HID;             // MK*1024
    bf16* h_b    = kv_b + (size_t)MK * EMB;               // MQ*512
    bf16* q16    = h_b + (size_t)MQ * HID;                // MQ*512
    bf16* kv16   = q16 + (size_t)MQ * HID;                // MK*1024 (k|v fused)
    bf16* qbt    = kv16 + (size_t)MK * EMB;               // MQ*512
    bf16* kbt    = qbt + (size_t)MQ * HID;                // MK*512
    bf16* Vt     = kbt + (size_t)MK * HID;                // 8*128*2048
    bf16* Wq_in_t = Vt + (size_t)8 * HD * ROWS_K;         // 512*896
    bf16* Wq_t  = Wq_in_t + 512 * 896;                    // 512*512
    bf16* kvw_t = Wq_t + 512 * 512;                       // 1024*1024 (Wk_t | Wv_t)
    bf16* Wo_t  = kvw_t + 1024 * 1024;                    // 512*512
    bf16* W1_t  = Wo_t + 512 * 512;                       // 1024*512
    bf16* W2_t  = W1_t + 1024 * 512;                      // 512*1024
    bf16* M1_t  = W2_t + 512 * 1024;                      // 1024*512
    bf16* M2_t  = M1_t + 1024 * 512;                      // 896*1024
    bf16* slow_b = shared_b;
    bf16* attn_b = shared_b;
    bf16* ff1_b  = shared_b;
    bf16* m1_b   = shared_b;

    dim3 blk(256);

    // ---- all weight transposes in one launch ----
    TDescs td;
    int t0 = 0;
    auto set = [&](int i, const float* s, bf16* d, int K, int N) {
        td.d[i] = {s, d, K, N, t0};
        t0 += (N / 32) * (K / 32);
    };
    set(0, Wq_in, Wq_in_t, 896, 512);
    set(1, Wq,    Wq_t,    512, 512);
    set(2, Wk,    kvw_t,              1024, 512);
    set(3, Wv,    kvw_t + 512 * 1024, 1024, 512);
    set(4, Wo,    Wo_t,    512, 512);
    set(5, W1,    W1_t,    512, 1024);
    set(6, W2,    W2_t,    1024, 512);
    set(7, M1,    M1_t,    512, 1024);
    set(8, M2,    M2_t,    1024, 896);
    transpose_all<<<t0, blk, 0, stream>>>(td);

    // bias concat for fused KV GEMM
    hipMemcpyAsync(bkv,       bk, 512 * sizeof(float), hipMemcpyDeviceToDevice, stream);
    hipMemcpyAsync(bkv + 512, bv, 512 * sizeof(float), hipMemcpyDeviceToDevice, stream);

    cvt_kernel<<<(MQ * DQ / 4 + 255) / 256, blk, 0, stream>>>(slow, slow_b, MQ * DQ / 4);
    kv_kernel<<<(MK * EMB) / 256, blk, 0, stream>>>(x, Wm, bm, kv_b);

    // q_in = slow @ Wq_in + bq_in -> fp32 (residual) + bf16   grid 4x196
    mgemm64<OP_BIAS, true, true><<<dim3(4, 196), blk, 0, stream>>>(
        slow_b, Wq_in_t, bq_in, nullptr, q_in_f, q_in_b, MQ, HID, DQ);
    // q projection -> bf16   grid 4x196
    mgemm64<OP_BIAS, false, true><<<dim3(4, 196), blk, 0, stream>>>(
        q_in_b, Wq_t, bq, nullptr, nullptr, q16, MQ, HID, HID);
    // fused k|v projection -> kv16 (MK x 1024)   grid 8x64
    mgemm64<OP_BIAS, false, true><<<dim3(8, 64), blk, 0, stream>>>(
        kv_b, kvw_t, bkv, nullptr, nullptr, kv16, MK, 1024, EMB);
    // RoPE (q pre-scaled by 1/sqrt(128)); k read from fused kv16
    rope_b_kernel<<<(MQ * 128 + 255) / 256, blk, 0, stream>>>(
        q16, qbt, ROWS_Q, 196, 14, MQ * 128, 0.08838834764831843f, 512, 0);
    rope_b_kernel<<<(MK * 128 + 255) / 256, blk, 0, stream>>>(
        kv16, kbt, ROWS_K, 64, 8, MK * 128, 1.0f, 1024, 0);
    // V transpose (coalesced)
    vt_tiled<<<dim3(32, 2, 8), blk, 0, stream>>>(kv16, Vt);
    // MFMA flash attention -> attn_b (bf16), 64 queries/block, grid 784
    mattn_kernel<<<dim3(784), blk, 0, stream>>>(qbt, kbt, Vt, attn_b);
    // pre_ln = attn @ Wo + bo + q_in   grid 4x196
    mgemm64<OP_RES, true, false><<<dim3(4, 196), blk, 0, stream>>>(
        attn_b, Wo_t, bo, q_in_f, ob, nullptr, MQ, HID, HID);
    ln_kernel<<<MQ / 4, blk, 0, stream>>>(ob, g1, be1, h_b);
    // ff1 = gelu(h @ W1 + b1)   grid 8x98 (128-tile)
    mgemm<OP_GELU, false, true><<<dim3(8, 98), blk, 0, stream>>>(
        h_b, W1_t, b1, nullptr, nullptr, ff1_b, MQ, FF, HID);
    // pre2 = ff1 @ W2 + b2 + h   grid 4x196
    mgemm64<OP_RES, true, false><<<dim3(4, 196), blk, 0, stream>>>(
        ff1_b, W2_t, b2, ob, q_in_f, nullptr, MQ, HID, FF);
    ln_kernel<<<MQ / 4, blk, 0, stream>>>(q_in_f, g2, be2, h_b);
    // m1 = gelu(h2 @ M1 + bm1)   grid 8x98
    mgemm<OP_GELU, false, true><<<dim3(8, 98), blk, 0, stream>>>(
        h_b, M1_t, bm1, nullptr, nullptr, m1_b, MQ, 2 * HID, HID);
    // out = m1 @ M2 + bm2   grid 7x98
    mgemm<OP_BIAS, true, false><<<dim3(7, 98), blk, 0, stream>>>(
        m1_b, M2_t, bm2, nullptr, out, nullptr, MQ, OUTD, 2 * HID);
}

// Round 3
// 800.873 us; speedup vs baseline: 1.3199x; 1.3199x over previous
//
#include <hip/hip_runtime.h>
#include <cstdint>
#include <cstddef>

// ---------------- dims ----------------
#define BATCH 2
#define MQ 12544          // B * TQ * NQ
#define ROWS_Q 6272
#define MK 4096           // B * T*H*W
#define ROWS_K 2048
#define HID 512
#define NH 4
#define HD 128
#define EMB 1024
#define DQ 896
#define FF 1024
#define OUTD 896

typedef __bf16 bf16;
typedef unsigned int u32;
typedef bf16 bf16x8 __attribute__((ext_vector_type(8)));
typedef bf16 bf16x4 __attribute__((ext_vector_type(4)));
typedef float f32x4 __attribute__((ext_vector_type(4)));

enum { OP_BIAS = 0, OP_GELU = 1, OP_RES = 2 };

__device__ __forceinline__ float gelu_tanh(float x) {
    float x3 = x * x * x;
    return 0.5f * x * (1.0f + tanhf(0.7978845608028654f * (x + 0.044715f * x3)));
}

__device__ __forceinline__ void gld16(const bf16* g, bf16* l) {
    __builtin_amdgcn_global_load_lds(
        (const __attribute__((address_space(1))) unsigned int*)g,
        (__attribute__((address_space(3))) unsigned int*)l, 16, 0, 0);
}

__device__ __forceinline__ u32 pack_bf16(float a, float b) {
    union { bf16 h[2]; u32 w; } u;
    u.h[0] = (bf16)a; u.h[1] = (bf16)b;
    return u.w;
}

// ---------------------------------------------------------------------------
// bf16 MFMA GEMM, 128x128 tile (m97 structure). For N>=1024-ish shapes.
// ---------------------------------------------------------------------------
template <int OP, bool WF32, bool WB16>
__global__ __launch_bounds__(256) void mgemm(
    const bf16* __restrict__ A, const bf16* __restrict__ Bt,
    const float* __restrict__ bias, const float* __restrict__ res,
    float* __restrict__ Cf, bf16* __restrict__ Cb, int M, int N, int K)
{
    __shared__ __align__(16) bf16 As[128 * 32];
    __shared__ __align__(16) bf16 Bs[128 * 32];
    const int tid  = threadIdx.x;
    const int m0   = blockIdx.y * 128;
    const int n0   = blockIdx.x * 128;
    const int wave = tid >> 6, lane = tid & 63;
    const int wm = (wave >> 1) * 64, wn = (wave & 1) * 64;

    f32x4 acc[4][4] = {};

    const int srow = tid >> 2;
    const int scol = (tid & 3) * 8;
    const bf16* Ag = A  + (size_t)(m0 + srow) * K + scol;
    const bf16* Bg = Bt + (size_t)(n0 + srow) * K + scol;
    bf16* Al = &As[tid * 8];
    bf16* Bl = &Bs[tid * 8];
    const size_t half = (size_t)64 * K;

    const int fr = lane & 15;
    const int kq = (lane >> 4) * 8;
    const bf16* pa = &As[(wm + fr) * 32 + kq];
    const bf16* pb = &Bs[(wn + fr) * 32 + kq];

    for (int k0 = 0; k0 < K; k0 += 32) {
        gld16(Ag + k0,        Al);
        gld16(Ag + k0 + half, Al + 64 * 32);
        gld16(Bg + k0,        Bl);
        gld16(Bg + k0 + half, Bl + 64 * 32);
        __syncthreads();

        bf16x8 af[4], bfr[4];
        #pragma unroll
        for (int i = 0; i < 4; ++i) af[i]  = *(const bf16x8*)(pa + i * 16 * 32);
        #pragma unroll
        for (int j = 0; j < 4; ++j) bfr[j] = *(const bf16x8*)(pb + j * 16 * 32);
        #pragma unroll
        for (int i = 0; i < 4; ++i)
            #pragma unroll
            for (int j = 0; j < 4; ++j)
                acc[i][j] = __builtin_amdgcn_mfma_f32_16x16x32_bf16(
                    af[i], bfr[j], acc[i][j], 0, 0, 0);
        __syncthreads();
    }

    const int colb = n0 + wn + (lane & 15);
    const int rowb = m0 + wm + (lane >> 4) * 4;
    #pragma unroll
    for (int i = 0; i < 4; ++i) {
        #pragma unroll
        for (int j = 0; j < 4; ++j) {
            const int c = colb + j * 16;
            const float bj = bias[c];
            #pragma unroll
            for (int r = 0; r < 4; ++r) {
                const int m = rowb + i * 16 + r;
                float v = acc[i][j][r] + bj;
                if (OP == OP_GELU) v = gelu_tanh(v);
                if (OP == OP_RES)  v += res[(size_t)m * N + c];
                if (WF32) Cf[(size_t)m * N + c] = v;
                if (WB16) Cb[(size_t)m * N + c] = (bf16)v;
            }
        }
    }
}

// ---------------------------------------------------------------------------
// bf16 MFMA GEMM, 64x128 tile: doubles grid for occupancy-starved shapes.
// 4 waves as 2(m)x2(n); each wave 32m x 64n (acc 2x4). LDS 12 KB.
// ---------------------------------------------------------------------------
template <int OP, bool WF32, bool WB16>
__global__ __launch_bounds__(256) void mgemm64(
    const bf16* __restrict__ A, const bf16* __restrict__ Bt,
    const float* __restrict__ bias, const float* __restrict__ res,
    float* __restrict__ Cf, bf16* __restrict__ Cb, int M, int N, int K)
{
    __shared__ __align__(16) bf16 As[64 * 32];
    __shared__ __align__(16) bf16 Bs[128 * 32];
    const int tid  = threadIdx.x;
    const int m0   = blockIdx.y * 64;
    const int n0   = blockIdx.x * 128;
    const int wave = tid >> 6, lane = tid & 63;
    const int wm = (wave >> 1) * 32, wn = (wave & 1) * 64;

    f32x4 acc[2][4] = {};

    const int srow = tid >> 2;
    const int scol = (tid & 3) * 8;
    const bf16* Ag = A  + (size_t)(m0 + srow) * K + scol;
    const bf16* Bg = Bt + (size_t)(n0 + srow) * K + scol;
    bf16* Al = &As[tid * 8];
    bf16* Bl = &Bs[tid * 8];
    const size_t half = (size_t)64 * K;

    const int fr = lane & 15;
    const int kq = (lane >> 4) * 8;
    const bf16* pa = &As[(wm + fr) * 32 + kq];
    const bf16* pb = &Bs[(wn + fr) * 32 + kq];

    for (int k0 = 0; k0 < K; k0 += 32) {
        gld16(Ag + k0,        Al);
        gld16(Bg + k0,        Bl);
        gld16(Bg + k0 + half, Bl + 64 * 32);
        __syncthreads();

        bf16x8 af[2], bfr[4];
        #pragma unroll
        for (int i = 0; i < 2; ++i) af[i]  = *(const bf16x8*)(pa + i * 16 * 32);
        #pragma unroll
        for (int j = 0; j < 4; ++j) bfr[j] = *(const bf16x8*)(pb + j * 16 * 32);
        #pragma unroll
        for (int i = 0; i < 2; ++i)
            #pragma unroll
            for (int j = 0; j < 4; ++j)
                acc[i][j] = __builtin_amdgcn_mfma_f32_16x16x32_bf16(
                    af[i], bfr[j], acc[i][j], 0, 0, 0);
        __syncthreads();
    }

    const int colb = n0 + wn + (lane & 15);
    const int rowb = m0 + wm + (lane >> 4) * 4;
    #pragma unroll
    for (int i = 0; i < 2; ++i) {
        #pragma unroll
        for (int j = 0; j < 4; ++j) {
            const int c = colb + j * 16;
            const float bj = bias[c];
            #pragma unroll
            for (int r = 0; r < 4; ++r) {
                const int m = rowb + i * 16 + r;
                float v = acc[i][j][r] + bj;
                if (OP == OP_GELU) v = gelu_tanh(v);
                if (OP == OP_RES)  v += res[(size_t)m * N + c];
                if (WF32) Cf[(size_t)m * N + c] = v;
                if (WB16) Cb[(size_t)m * N + c] = (bf16)v;
            }
        }
    }
}

// ---------------------------------------------------------------------------
// All 9 weight transposes (fp32 KxN -> bf16 NxK) in ONE launch.
// ---------------------------------------------------------------------------
struct TDesc { const float* src; bf16* dst; int K; int N; int tile0; };
struct TDescs { TDesc d[9]; };

__global__ __launch_bounds__(256) void transpose_all(TDescs td)
{
    __shared__ float t[32][33];
    const int blk = blockIdx.x;
    int i = 0;
    #pragma unroll
    for (int j = 1; j < 9; ++j) if (blk >= td.d[j].tile0) i = j;
    const float* src = td.d[i].src;
    bf16* dst = td.d[i].dst;
    const int K = td.d[i].K, N = td.d[i].N;
    const int local = blk - td.d[i].tile0;
    const int ntx = N >> 5;
    const int bx = local % ntx, by = local / ntx;
    const int x = threadIdx.x & 31, y = threadIdx.x >> 5;
    #pragma unroll
    for (int p = 0; p < 32; p += 8)
        t[y + p][x] = src[(size_t)(by * 32 + y + p) * N + bx * 32 + x];
    __syncthreads();
    #pragma unroll
    for (int p = 0; p < 32; p += 8)
        dst[(size_t)(bx * 32 + y + p) * K + by * 32 + x] = (bf16)t[x][y + p];
}

// fp32 -> bf16 elementwise
__global__ __launch_bounds__(256) void cvt_kernel(
    const float* __restrict__ in, bf16* __restrict__ out, int n4)
{
    int i = blockIdx.x * 256 + threadIdx.x;
    if (i >= n4) return;
    float4 v = ((const float4*)in)[i];
    out[4 * i + 0] = (bf16)v.x;
    out[4 * i + 1] = (bf16)v.y;
    out[4 * i + 2] = (bf16)v.z;
    out[4 * i + 3] = (bf16)v.w;
}

// kv = x @ Wm + bm  (K=4), bf16 out.
__global__ __launch_bounds__(256) void kv_kernel(
    const float* __restrict__ x, const float* __restrict__ Wm,
    const float* __restrict__ bm, bf16* __restrict__ kv)
{
    int idx = blockIdx.x * 256 + threadIdx.x;
    int r = idx >> 10, n = idx & 1023;
    float4 xv = *(const float4*)(x + (size_t)r * 4);
    float v = bm[n] + xv.x * Wm[n] + xv.y * Wm[1024 + n]
                    + xv.z * Wm[2048 + n] + xv.w * Wm[3072 + n];
    kv[idx] = (bf16)v;
}

// 3D RoPE: bf16 in (row stride istr, col offset icoff) -> bf16 out (rows x 512).
__global__ __launch_bounds__(256) void rope_b_kernel(
    const bf16* __restrict__ in, bf16* __restrict__ out,
    int tok, int gdiv, int wdiv, int total, float sc, int istr, int icoff)
{
    int idx = blockIdx.x * 256 + threadIdx.x;
    if (idx >= total) return;
    int row = idx >> 7;
    int r2 = idx & 127;
    int h = r2 >> 5;
    int j2 = r2 & 31;
    int j = 2 * j2;
    int n = row % tok;
    int t = n / gdiv;
    int g = n % gdiv;
    int gh = g / wdiv;
    int gw = g % wdiv;
    float pa = (j < 22) ? (float)t : (j < 43) ? (float)gh : (float)gw;
    int j1 = j + 1;
    float pb = (j1 < 22) ? (float)t : (j1 < 43) ? (float)gh : (float)gw;
    float fra = pa * exp2f(-(float)j  * 0.20762050593045954f);
    float frb = pb * exp2f(-(float)j1 * 0.20762050593045954f);
    float ca = cosf(fra), sa = sinf(fra);
    float cb = cosf(frb), sb = sinf(frb);
    size_t ibase = (size_t)row * istr + icoff + (size_t)h * 128 + j;
    size_t obase = (size_t)row * 512 + (size_t)h * 128 + j;
    union { u32 w; bf16 e[2]; } ua, ub;
    ua.w = *(const u32*)(in + ibase);
    ub.w = *(const u32*)(in + ibase + 64);
    float x1a = (float)ua.e[0], x1b = (float)ua.e[1];
    float x2a = (float)ub.e[0], x2b = (float)ub.e[1];
    *(u32*)(out + obase)      = pack_bf16((x1a * ca - x2a * sa) * sc,
                                          (x1b * cb - x2b * sb) * sc);
    *(u32*)(out + obase + 64) = pack_bf16((x2a * ca + x1a * sa) * sc,
                                          (x2b * cb + x1b * sb) * sc);
}

// Coalesced V transpose: kv16[t][512 + h*128 + d] -> Vt[b][h][d][2048]
__global__ __launch_bounds__(256) void vt_tiled(
    const bf16* __restrict__ kv16, bf16* __restrict__ vt)
{
    __shared__ bf16 t[64][72];
    const int tt = blockIdx.x * 64;
    const int d0 = blockIdx.y * 64;
    const int bh = blockIdx.z;
    const int b = bh >> 2, h = bh & 3;
    const int rr = threadIdx.x >> 4;
    const int cc = (threadIdx.x & 15) * 4;
    #pragma unroll
    for (int p = 0; p < 4; ++p) {
        int r = rr + p * 16;
        *(bf16x4*)&t[r][cc] = *(const bf16x4*)
            (kv16 + (size_t)(b * ROWS_K + tt + r) * 1024 + 512 + h * 128 + d0 + cc);
    }
    __syncthreads();
    #pragma unroll
    for (int p = 0; p < 4; ++p) {
        int r = rr + p * 16;   // d-local
        bf16x4 v;
        v[0] = t[cc + 0][r]; v[1] = t[cc + 1][r];
        v[2] = t[cc + 2][r]; v[3] = t[cc + 3][r];
        *(bf16x4*)(vt + (size_t)bh * HD * ROWS_K + (size_t)(d0 + r) * ROWS_K + tt + cc) = v;
    }
}

// LayerNorm in-place on (rows x 512) + bf16 copy.
__global__ __launch_bounds__(256) void ln_kernel(
    float* __restrict__ xb, const float* __restrict__ g,
    const float* __restrict__ be, bf16* __restrict__ out16)
{
    int wave = threadIdx.x >> 6, lane = threadIdx.x & 63;
    size_t row = (size_t)blockIdx.x * 4 + wave;
    float* xp = xb + row * 512;
    float4 a = ((const float4*)xp)[lane];
    float4 b = ((const float4*)xp)[lane + 64];
    float s  = a.x + a.y + a.z + a.w + b.x + b.y + b.z + b.w;
    float sq = a.x*a.x + a.y*a.y + a.z*a.z + a.w*a.w
             + b.x*b.x + b.y*b.y + b.z*b.z + b.w*b.w;
    #pragma unroll
    for (int off = 32; off; off >>= 1) {
        s  += __shfl_xor(s, off);
        sq += __shfl_xor(sq, off);
    }
    float mean = s * (1.0f / 512.0f);
    float var  = sq * (1.0f / 512.0f) - mean * mean;
    float rstd = rsqrtf(var + 1e-5f);
    float4 gv1 = ((const float4*)g)[lane],  gv2 = ((const float4*)g)[lane + 64];
    float4 bv1 = ((const float4*)be)[lane], bv2 = ((const float4*)be)[lane + 64];
    a.x = (a.x - mean) * rstd * gv1.x + bv1.x;
    a.y = (a.y - mean) * rstd * gv1.y + bv1.y;
    a.z = (a.z - mean) * rstd * gv1.z + bv1.z;
    a.w = (a.w - mean) * rstd * gv1.w + bv1.w;
    b.x = (b.x - mean) * rstd * gv2.x + bv2.x;
    b.y = (b.y - mean) * rstd * gv2.y + bv2.y;
    b.z = (b.z - mean) * rstd * gv2.z + bv2.z;
    b.w = (b.w - mean) * rstd * gv2.w + bv2.w;
    ((float4*)xp)[lane]      = a;
    ((float4*)xp)[lane + 64] = b;
    bf16* op = out16 + row * 512;
    *(u32*)(op + lane * 4)       = pack_bf16(a.x, a.y);
    *(u32*)(op + lane * 4 + 2)   = pack_bf16(a.z, a.w);
    *(u32*)(op + 256 + lane * 4)     = pack_bf16(b.x, b.y);
    *(u32*)(op + 256 + lane * 4 + 2) = pack_bf16(b.z, b.w);
}

// ---------------------------------------------------------------------------
// MFMA flash attention (bf16, fp32 accum).
// Round-3 = exact round-0 structure (4 waves x 32 q, grid 392, VGPR-heavy;
// the 16q/wave restructures of rounds 1-2 let the allocator squeeze into the
// 64-VGPR max-occupancy bucket, serializing ds_read->MFMA: 5x regression).
// Deltas vs round 0, each individually validated:
//   - LDS strides 6 mod 32 dwords (K:140, V:76, O:140): conflicts 11.4M->3.3M
//   - reg-staged double-buffered K/V (T14): next tile's global loads issued
//     at loop top, in flight under the current tile's compute; ds_write after
//     the barrier. Removes the per-iter exposed global-load latency.
//   - exact defer-rescale: skip O/l rescale when no row's max grew (alpha==1).
// LDS: 2 x (64*140 + 128*76) * 2B = 74752 B -> 2 blocks/CU (same residency).
// ---------------------------------------------------------------------------
#define KS 140
#define VS 76
#define OS 140
#define KBYTES 17920    // 64*KS*2
#define VBYTES 19456    // 128*VS*2
#define BUFB 37376      // KBYTES+VBYTES

__global__ __launch_bounds__(256, 2) void mattn_kernel(
    const bf16* __restrict__ qs, const bf16* __restrict__ ks,
    const bf16* __restrict__ vt, bf16* __restrict__ outb)
{
    __shared__ __align__(16) char smem[2 * BUFB];

    const int tid = threadIdx.x;
    const int wave = tid >> 6, lane = tid & 63;
    const int quad = lane >> 4, c = lane & 15;
    const int bid = blockIdx.x;
    const int qt = bid % 49;
    const int h  = (bid / 49) & 3;
    const int b  = bid / 196;

    const int q0 = qt * 128 + wave * 32;
    const bf16* qg = qs + (size_t)(b * ROWS_Q + q0) * HID + h * HD;
    const bf16* kg = ks + (size_t)(b * ROWS_K) * HID + h * HD;
    const bf16* vg = vt + (size_t)(b * NH + h) * HD * ROWS_K;

    bf16x8 qf[2][4];
    #pragma unroll
    for (int n = 0; n < 2; ++n)
        #pragma unroll
        for (int s = 0; s < 4; ++s)
            qf[n][s] = *(const bf16x8*)(qg + (size_t)(n * 16 + c) * HID + s * 32 + quad * 8);

    f32x4 o[8][2] = {};
    float m_i[2] = {-1e30f, -1e30f}, l_i[2] = {0.0f, 0.0f};

    // staging: K 64x128 (4 b128/thread), V 128x64 (4 b128/thread)
    const int st_t = tid >> 2;
    const int st_d = (tid & 3) * 32;
    const int sv_d = tid >> 1;
    const int sv_t = (tid & 1) * 32;
    const bf16* ksrc = kg + (size_t)st_t * HID + st_d;
    const bf16* vsrc = vg + (size_t)sv_d * ROWS_K + sv_t;

    // prologue: tile 0 -> regs -> buf0
    bf16x8 rK[4], rV[4];
    #pragma unroll
    for (int i = 0; i < 4; ++i) rK[i] = *(const bf16x8*)(ksrc + i * 8);
    #pragma unroll
    for (int i = 0; i < 4; ++i) rV[i] = *(const bf16x8*)(vsrc + i * 8);
    {
        bf16* Kd = (bf16*)smem + st_t * KS + st_d;
        bf16* Vd = (bf16*)(smem + KBYTES) + sv_d * VS + sv_t;
        #pragma unroll
        for (int i = 0; i < 4; ++i) *(bf16x8*)(Kd + i * 8) = rK[i];
        #pragma unroll
        for (int i = 0; i < 4; ++i) *(bf16x8*)(Vd + i * 8) = rV[i];
    }
    __syncthreads();

    for (int kt = 0; kt < 32; ++kt) {
        const int cur = kt & 1;
        const bf16* Ksh = (const bf16*)(smem + cur * BUFB);
        const bf16* Vsh = (const bf16*)(smem + cur * BUFB + KBYTES);

        // issue next tile's global loads; they fly under this tile's compute
        if (kt < 31) {
            const bf16* s1 = ksrc + (size_t)(kt + 1) * 64 * HID;
            const bf16* s2 = vsrc + (kt + 1) * 64;
            #pragma unroll
            for (int i = 0; i < 4; ++i) rK[i] = *(const bf16x8*)(s1 + i * 8);
            #pragma unroll
            for (int i = 0; i < 4; ++i) rV[i] = *(const bf16x8*)(s2 + i * 8);
        }

        // QK^T: s[mi][n][r] = score(k = mi*16 + quad*4 + r, q = n*16 + c)
        f32x4 s[4][2] = {};
        #pragma unroll
        for (int ksi = 0; ksi < 4; ++ksi) {
            bf16x8 kf[4];
            #pragma unroll
            for (int mi = 0; mi < 4; ++mi)
                kf[mi] = *(const bf16x8*)(Ksh + (mi * 16 + c) * KS + ksi * 32 + quad * 8);
            #pragma unroll
            for (int mi = 0; mi < 4; ++mi)
                #pragma unroll
                for (int n = 0; n < 2; ++n)
                    s[mi][n] = __builtin_amdgcn_mfma_f32_16x16x32_bf16(
                        kf[mi], qf[n][ksi], s[mi][n], 0, 0, 0);
        }

        // online softmax
        float mx[2];
        #pragma unroll
        for (int n = 0; n < 2; ++n) {
            float m = -1e30f;
            #pragma unroll
            for (int mi = 0; mi < 4; ++mi)
                #pragma unroll
                for (int r = 0; r < 4; ++r) m = fmaxf(m, s[mi][n][r]);
            m = fmaxf(m, __shfl_xor(m, 16));
            m = fmaxf(m, __shfl_xor(m, 32));
            mx[n] = m;
        }
        if (!__all((mx[0] <= m_i[0]) && (mx[1] <= m_i[1]))) {
            #pragma unroll
            for (int n = 0; n < 2; ++n) {
                float mn = fmaxf(m_i[n], mx[n]);
                float alpha = __expf(m_i[n] - mn);
                m_i[n] = mn;
                l_i[n] *= alpha;
                #pragma unroll
                for (int md = 0; md < 8; ++md) {
                    o[md][n][0] *= alpha; o[md][n][1] *= alpha;
                    o[md][n][2] *= alpha; o[md][n][3] *= alpha;
                }
            }
        }
        #pragma unroll
        for (int n = 0; n < 2; ++n) {
            float sm = 0.0f;
            #pragma unroll
            for (int mi = 0; mi < 4; ++mi)
                #pragma unroll
                for (int r = 0; r < 4; ++r) {
                    float p = __expf(s[mi][n][r] - m_i[n]);
                    s[mi][n][r] = p;
                    sm += p;
                }
            sm += __shfl_xor(sm, 16);
            sm += __shfl_xor(sm, 32);
            l_i[n] += sm;
        }

        // repack P (rows=k, cols=q) into PV B-operand fragments
        u32 pk[4][2][2];
        #pragma unroll
        for (int mi = 0; mi < 4; ++mi)
            #pragma unroll
            for (int n = 0; n < 2; ++n) {
                pk[mi][n][0] = pack_bf16(s[mi][n][0], s[mi][n][1]);
                pk[mi][n][1] = pack_bf16(s[mi][n][2], s[mi][n][3]);
            }
        bf16x8 pf[2][2];
        #pragma unroll
        for (int kst = 0; kst < 2; ++kst)
            #pragma unroll
            for (int n = 0; n < 2; ++n) {
                union { bf16x8 v8; u32 d[4]; } u;
                #pragma unroll
                for (int dw = 0; dw < 4; ++dw) {
                    int srcl = ((quad & 1) * 2 + (dw >> 1)) * 16 + c;
                    u32 lo = (u32)__shfl((int)pk[2 * kst][n][dw & 1], srcl);
                    u32 hi = (u32)__shfl((int)pk[2 * kst + 1][n][dw & 1], srcl);
                    u.d[dw] = (quad >= 2) ? hi : lo;
                }
                pf[kst][n] = u.v8;
            }

        // PV: o[md][n][r] = O(q=n*16+c, d = md*16 + quad*4 + r)
        #pragma unroll
        for (int kst = 0; kst < 2; ++kst)
            #pragma unroll
            for (int md = 0; md < 8; ++md) {
                bf16x8 vf = *(const bf16x8*)(Vsh + (md * 16 + c) * VS + kst * 32 + quad * 8);
                #pragma unroll
                for (int n = 0; n < 2; ++n)
                    o[md][n] = __builtin_amdgcn_mfma_f32_16x16x32_bf16(
                        vf, pf[kst][n], o[md][n], 0, 0, 0);
            }

        // write next tile into the other buffer
        if (kt < 31) {
            __syncthreads();
            bf16* Kd = (bf16*)(smem + (cur ^ 1) * BUFB) + st_t * KS + st_d;
            bf16* Vd = (bf16*)(smem + (cur ^ 1) * BUFB + KBYTES) + sv_d * VS + sv_t;
            #pragma unroll
            for (int i = 0; i < 4; ++i) *(bf16x8*)(Kd + i * 8) = rK[i];
            #pragma unroll
            for (int i = 0; i < 4; ++i) *(bf16x8*)(Vd + i * 8) = rV[i];
            __syncthreads();
        }
    }

    __syncthreads();
    bf16* Osh = (bf16*)smem + wave * (32 * OS);
    float inv[2] = {1.0f / l_i[0], 1.0f / l_i[1]};
    #pragma unroll
    for (int md = 0; md < 8; ++md)
        #pragma unroll
        for (int n = 0; n < 2; ++n)
            #pragma unroll
            for (int hh = 0; hh < 2; ++hh) {
                u32 w = pack_bf16(o[md][n][2 * hh] * inv[n], o[md][n][2 * hh + 1] * inv[n]);
                int d = md * 16 + quad * 4 + 2 * hh;
                int qq = n * 16 + c;
                *(u32*)(Osh + qq * OS + d) = w;
            }
    __syncthreads();
    bf16* og = outb + (size_t)(b * ROWS_Q + q0) * HID + h * HD;
    #pragma unroll
    for (int i = 0; i < 8; ++i) {
        int idx = i * 64 + lane;
        int qq = idx >> 4;
        int ch = idx & 15;
        bf16x8 vv = *(const bf16x8*)(Osh + qq * OS + ch * 8);
        *(bf16x8*)(og + (size_t)qq * HID + ch * 8) = vv;
    }
}

extern "C" void kernel_launch(void* const* d_in, const int* in_sizes, int n_in,
                              void* d_out, int out_size, void* d_ws, size_t ws_size,
                              hipStream_t stream)
{
    const float* x     = (const float*)d_in[0];
    const float* slow  = (const float*)d_in[1];
    const float* Wq_in = (const float*)d_in[3];
    const float* bq_in = (const float*)d_in[4];
    const float* Wm    = (const float*)d_in[5];
    const float* bm    = (const float*)d_in[6];
    const float* Wq    = (const float*)d_in[7];
    const float* bq    = (const float*)d_in[8];
    const float* Wk    = (const float*)d_in[9];
    const float* bk    = (const float*)d_in[10];
    const float* Wv    = (const float*)d_in[11];
    const float* bv    = (const float*)d_in[12];
    const float* Wo    = (const float*)d_in[13];
    const float* bo    = (const float*)d_in[14];
    const float* g1    = (const float*)d_in[15];
    const float* be1   = (const float*)d_in[16];
    const float* W1    = (const float*)d_in[17];
    const float* b1    = (const float*)d_in[18];
    const float* W2    = (const float*)d_in[19];
    const float* b2    = (const float*)d_in[20];
    const float* g2    = (const float*)d_in[21];
    const float* be2   = (const float*)d_in[22];
    const float* M1    = (const float*)d_in[23];
    const float* bm1   = (const float*)d_in[24];
    const float* M2    = (const float*)d_in[25];
    const float* bm2   = (const float*)d_in[26];
    float* out = (float*)d_out;

    // ---- workspace layout ----
    float* q_in_f = (float*)d_ws;                         // MQ*512 f32
    float* ob     = q_in_f + (size_t)MQ * HID;            // MQ*512 f32
    float* bkv    = ob + (size_t)MQ * HID;                // 1024 f32
    bf16* shared_b = (bf16*)(bkv + 1024);                 // MQ*1024 (slow_b/attn_b/ff1_b/m1_b)
    bf16* q_in_b = shared_b + (size_t)MQ * FF;            // MQ*512
    bf16* kv_b   = q_in_b + (size_t)MQ * HID;             // MK*1024
    bf16* h_b    = kv_b + (size_t)MK * EMB;               // MQ*512
    bf16* q16    = h_b + (size_t)MQ * HID;                // MQ*512
    bf16* kv16   = q16 + (size_t)MQ * HID;                // MK*1024 (k|v fused)
    bf16* qbt    = kv16 + (size_t)MK * EMB;               // MQ*512
    bf16* kbt    = qbt + (size_t)MQ * HID;                // MK*512
    bf16* Vt     = kbt + (size_t)MK * HID;                // 8*128*2048
    bf16* Wq_in_t = Vt + (size_t)8 * HD * ROWS_K;         // 512*896
    bf16* Wq_t  = Wq_in_t + 512 * 896;                    // 512*512
    bf16* kvw_t = Wq_t + 512 * 512;                       // 1024*1024 (Wk_t | Wv_t)
    bf16* Wo_t  = kvw_t + 1024 * 1024;                    // 512*512
    bf16* W1_t  = Wo_t + 512 * 512;                       // 1024*512
    bf16* W2_t  = W1_t + 1024 * 512;                      // 512*1024
    bf16* M1_t  = W2_t + 512 * 1024;                      // 1024*512
    bf16* M2_t  = M1_t + 1024 * 512;                      // 896*1024
    bf16* slow_b = shared_b;
    bf16* attn_b = shared_b;
    bf16* ff1_b  = shared_b;
    bf16* m1_b   = shared_b;

    dim3 blk(256);

    // ---- all weight transposes in one launch ----
    TDescs td;
    int t0 = 0;
    auto set = [&](int i, const float* s, bf16* d, int K, int N) {
        td.d[i] = {s, d, K, N, t0};
        t0 += (N / 32) * (K / 32);
    };
    set(0, Wq_in, Wq_in_t, 896, 512);
    set(1, Wq,    Wq_t,    512, 512);
    set(2, Wk,    kvw_t,              1024, 512);
    set(3, Wv,    kvw_t + 512 * 1024, 1024, 512);
    set(4, Wo,    Wo_t,    512, 512);
    set(5, W1,    W1_t,    512, 1024);
    set(6, W2,    W2_t,    1024, 512);
    set(7, M1,    M1_t,    512, 1024);
    set(8, M2,    M2_t,    1024, 896);
    transpose_all<<<t0, blk, 0, stream>>>(td);

    // bias concat for fused KV GEMM
    hipMemcpyAsync(bkv,       bk, 512 * sizeof(float), hipMemcpyDeviceToDevice, stream);
    hipMemcpyAsync(bkv + 512, bv, 512 * sizeof(float), hipMemcpyDeviceToDevice, stream);

    cvt_kernel<<<(MQ * DQ / 4 + 255) / 256, blk, 0, stream>>>(slow, slow_b, MQ * DQ / 4);
    kv_kernel<<<(MK * EMB) / 256, blk, 0, stream>>>(x, Wm, bm, kv_b);

    // q_in = slow @ Wq_in + bq_in -> fp32 (residual) + bf16   grid 4x196
    mgemm64<OP_BIAS, true, true><<<dim3(4, 196), blk, 0, stream>>>(
        slow_b, Wq_in_t, bq_in, nullptr, q_in_f, q_in_b, MQ, HID, DQ);
    // q projection -> bf16   grid 4x196
    mgemm64<OP_BIAS, false, true><<<dim3(4, 196), blk, 0, stream>>>(
        q_in_b, Wq_t, bq, nullptr, nullptr, q16, MQ, HID, HID);
    // fused k|v projection -> kv16 (MK x 1024)   grid 8x64
    mgemm64<OP_BIAS, false, true><<<dim3(8, 64), blk, 0, stream>>>(
        kv_b, kvw_t, bkv, nullptr, nullptr, kv16, MK, 1024, EMB);
    // RoPE (q pre-scaled by 1/sqrt(128)); k read from fused kv16
    rope_b_kernel<<<(MQ * 128 + 255) / 256, blk, 0, stream>>>(
        q16, qbt, ROWS_Q, 196, 14, MQ * 128, 0.08838834764831843f, 512, 0);
    rope_b_kernel<<<(MK * 128 + 255) / 256, blk, 0, stream>>>(
        kv16, kbt, ROWS_K, 64, 8, MK * 128, 1.0f, 1024, 0);
    // V transpose (coalesced)
    vt_tiled<<<dim3(32, 2, 8), blk, 0, stream>>>(kv16, Vt);
    // MFMA flash attention -> attn_b (bf16), grid 392 (round-0 structure)
    mattn_kernel<<<dim3(392), blk, 0, stream>>>(qbt, kbt, Vt, attn_b);
    // pre_ln = attn @ Wo + bo + q_in   grid 4x196
    mgemm64<OP_RES, true, false><<<dim3(4, 196), blk, 0, stream>>>(
        attn_b, Wo_t, bo, q_in_f, ob, nullptr, MQ, HID, HID);
    ln_kernel<<<MQ / 4, blk, 0, stream>>>(ob, g1, be1, h_b);
    // ff1 = gelu(h @ W1 + b1)   grid 8x98 (128-tile)
    mgemm<OP_GELU, false, true><<<dim3(8, 98), blk, 0, stream>>>(
        h_b, W1_t, b1, nullptr, nullptr, ff1_b, MQ, FF, HID);
    // pre2 = ff1 @ W2 + b2 + h   grid 4x196
    mgemm64<OP_RES, true, false><<<dim3(4, 196), blk, 0, stream>>>(
        ff1_b, W2_t, b2, ob, q_in_f, nullptr, MQ, HID, FF);
    ln_kernel<<<MQ / 4, blk, 0, stream>>>(q_in_f, g2, be2, h_b);
    // m1 = gelu(h2 @ M1 + bm1)   grid 8x98
    mgemm<OP_GELU, false, true><<<dim3(8, 98), blk, 0, stream>>>(
        h_b, M1_t, bm1, nullptr, nullptr, m1_b, MQ, 2 * HID, HID);
    // out = m1 @ M2 + bm2   grid 7x98
    mgemm<OP_BIAS, true, false><<<dim3(7, 98), blk, 0, stream>>>(
        m1_b, M2_t, bm2, nullptr, out, nullptr, MQ, OUTD, 2 * HID);
}

// Round 4
// 790.093 us; speedup vs baseline: 1.3379x; 1.0136x over previous
//
#include <hip/hip_runtime.h>
#include <cstdint>
#include <cstddef>

// ---------------- dims ----------------
#define BATCH 2
#define MQ 12544          // B * TQ * NQ
#define ROWS_Q 6272
#define MK 4096           // B * T*H*W
#define ROWS_K 2048
#define HID 512
#define NH 4
#define HD 128
#define EMB 1024
#define DQ 896
#define FF 1024
#define OUTD 896

typedef __bf16 bf16;
typedef unsigned int u32;
typedef bf16 bf16x8 __attribute__((ext_vector_type(8)));
typedef bf16 bf16x4 __attribute__((ext_vector_type(4)));
typedef float f32x4 __attribute__((ext_vector_type(4)));

enum { OP_BIAS = 0, OP_GELU = 1, OP_RES = 2 };

__device__ __forceinline__ float gelu_tanh(float x) {
    float x3 = x * x * x;
    return 0.5f * x * (1.0f + tanhf(0.7978845608028654f * (x + 0.044715f * x3)));
}

__device__ __forceinline__ void gld16(const bf16* g, bf16* l) {
    __builtin_amdgcn_global_load_lds(
        (const __attribute__((address_space(1))) unsigned int*)g,
        (__attribute__((address_space(3))) unsigned int*)l, 16, 0, 0);
}

__device__ __forceinline__ u32 pack_bf16(float a, float b) {
    union { bf16 h[2]; u32 w; } u;
    u.h[0] = (bf16)a; u.h[1] = (bf16)b;
    return u.w;
}

// ---------------------------------------------------------------------------
// bf16 MFMA GEMM, 128x128 tile (m97 structure). For N>=1024-ish shapes.
// ---------------------------------------------------------------------------
template <int OP, bool WF32, bool WB16>
__global__ __launch_bounds__(256) void mgemm(
    const bf16* __restrict__ A, const bf16* __restrict__ Bt,
    const float* __restrict__ bias, const float* __restrict__ res,
    float* __restrict__ Cf, bf16* __restrict__ Cb, int M, int N, int K)
{
    __shared__ __align__(16) bf16 As[128 * 32];
    __shared__ __align__(16) bf16 Bs[128 * 32];
    const int tid  = threadIdx.x;
    const int m0   = blockIdx.y * 128;
    const int n0   = blockIdx.x * 128;
    const int wave = tid >> 6, lane = tid & 63;
    const int wm = (wave >> 1) * 64, wn = (wave & 1) * 64;

    f32x4 acc[4][4] = {};

    const int srow = tid >> 2;
    const int scol = (tid & 3) * 8;
    const bf16* Ag = A  + (size_t)(m0 + srow) * K + scol;
    const bf16* Bg = Bt + (size_t)(n0 + srow) * K + scol;
    bf16* Al = &As[tid * 8];
    bf16* Bl = &Bs[tid * 8];
    const size_t half = (size_t)64 * K;

    const int fr = lane & 15;
    const int kq = (lane >> 4) * 8;
    const bf16* pa = &As[(wm + fr) * 32 + kq];
    const bf16* pb = &Bs[(wn + fr) * 32 + kq];

    for (int k0 = 0; k0 < K; k0 += 32) {
        gld16(Ag + k0,        Al);
        gld16(Ag + k0 + half, Al + 64 * 32);
        gld16(Bg + k0,        Bl);
        gld16(Bg + k0 + half, Bl + 64 * 32);
        __syncthreads();

        bf16x8 af[4], bfr[4];
        #pragma unroll
        for (int i = 0; i < 4; ++i) af[i]  = *(const bf16x8*)(pa + i * 16 * 32);
        #pragma unroll
        for (int j = 0; j < 4; ++j) bfr[j] = *(const bf16x8*)(pb + j * 16 * 32);
        #pragma unroll
        for (int i = 0; i < 4; ++i)
            #pragma unroll
            for (int j = 0; j < 4; ++j)
                acc[i][j] = __builtin_amdgcn_mfma_f32_16x16x32_bf16(
                    af[i], bfr[j], acc[i][j], 0, 0, 0);
        __syncthreads();
    }

    const int colb = n0 + wn + (lane & 15);
    const int rowb = m0 + wm + (lane >> 4) * 4;
    #pragma unroll
    for (int i = 0; i < 4; ++i) {
        #pragma unroll
        for (int j = 0; j < 4; ++j) {
            const int c = colb + j * 16;
            const float bj = bias[c];
            #pragma unroll
            for (int r = 0; r < 4; ++r) {
                const int m = rowb + i * 16 + r;
                float v = acc[i][j][r] + bj;
                if (OP == OP_GELU) v = gelu_tanh(v);
                if (OP == OP_RES)  v += res[(size_t)m * N + c];
                if (WF32) Cf[(size_t)m * N + c] = v;
                if (WB16) Cb[(size_t)m * N + c] = (bf16)v;
            }
        }
    }
}

// ---------------------------------------------------------------------------
// bf16 MFMA GEMM, 64x128 tile: doubles grid for occupancy-starved shapes.
// 4 waves as 2(m)x2(n); each wave 32m x 64n (acc 2x4). LDS 12 KB.
// ---------------------------------------------------------------------------
template <int OP, bool WF32, bool WB16>
__global__ __launch_bounds__(256) void mgemm64(
    const bf16* __restrict__ A, const bf16* __restrict__ Bt,
    const float* __restrict__ bias, const float* __restrict__ res,
    float* __restrict__ Cf, bf16* __restrict__ Cb, int M, int N, int K)
{
    __shared__ __align__(16) bf16 As[64 * 32];
    __shared__ __align__(16) bf16 Bs[128 * 32];
    const int tid  = threadIdx.x;
    const int m0   = blockIdx.y * 64;
    const int n0   = blockIdx.x * 128;
    const int wave = tid >> 6, lane = tid & 63;
    const int wm = (wave >> 1) * 32, wn = (wave & 1) * 64;

    f32x4 acc[2][4] = {};

    const int srow = tid >> 2;
    const int scol = (tid & 3) * 8;
    const bf16* Ag = A  + (size_t)(m0 + srow) * K + scol;
    const bf16* Bg = Bt + (size_t)(n0 + srow) * K + scol;
    bf16* Al = &As[tid * 8];
    bf16* Bl = &Bs[tid * 8];
    const size_t half = (size_t)64 * K;

    const int fr = lane & 15;
    const int kq = (lane >> 4) * 8;
    const bf16* pa = &As[(wm + fr) * 32 + kq];
    const bf16* pb = &Bs[(wn + fr) * 32 + kq];

    for (int k0 = 0; k0 < K; k0 += 32) {
        gld16(Ag + k0,        Al);
        gld16(Bg + k0,        Bl);
        gld16(Bg + k0 + half, Bl + 64 * 32);
        __syncthreads();

        bf16x8 af[2], bfr[4];
        #pragma unroll
        for (int i = 0; i < 2; ++i) af[i]  = *(const bf16x8*)(pa + i * 16 * 32);
        #pragma unroll
        for (int j = 0; j < 4; ++j) bfr[j] = *(const bf16x8*)(pb + j * 16 * 32);
        #pragma unroll
        for (int i = 0; i < 2; ++i)
            #pragma unroll
            for (int j = 0; j < 4; ++j)
                acc[i][j] = __builtin_amdgcn_mfma_f32_16x16x32_bf16(
                    af[i], bfr[j], acc[i][j], 0, 0, 0);
        __syncthreads();
    }

    const int colb = n0 + wn + (lane & 15);
    const int rowb = m0 + wm + (lane >> 4) * 4;
    #pragma unroll
    for (int i = 0; i < 2; ++i) {
        #pragma unroll
        for (int j = 0; j < 4; ++j) {
            const int c = colb + j * 16;
            const float bj = bias[c];
            #pragma unroll
            for (int r = 0; r < 4; ++r) {
                const int m = rowb + i * 16 + r;
                float v = acc[i][j][r] + bj;
                if (OP == OP_GELU) v = gelu_tanh(v);
                if (OP == OP_RES)  v += res[(size_t)m * N + c];
                if (WF32) Cf[(size_t)m * N + c] = v;
                if (WB16) Cb[(size_t)m * N + c] = (bf16)v;
            }
        }
    }
}

// ---------------------------------------------------------------------------
// All 9 weight transposes (fp32 KxN -> bf16 NxK) in ONE launch.
// ---------------------------------------------------------------------------
struct TDesc { const float* src; bf16* dst; int K; int N; int tile0; };
struct TDescs { TDesc d[9]; };

__global__ __launch_bounds__(256) void transpose_all(TDescs td)
{
    __shared__ float t[32][33];
    const int blk = blockIdx.x;
    int i = 0;
    #pragma unroll
    for (int j = 1; j < 9; ++j) if (blk >= td.d[j].tile0) i = j;
    const float* src = td.d[i].src;
    bf16* dst = td.d[i].dst;
    const int K = td.d[i].K, N = td.d[i].N;
    const int local = blk - td.d[i].tile0;
    const int ntx = N >> 5;
    const int bx = local % ntx, by = local / ntx;
    const int x = threadIdx.x & 31, y = threadIdx.x >> 5;
    #pragma unroll
    for (int p = 0; p < 32; p += 8)
        t[y + p][x] = src[(size_t)(by * 32 + y + p) * N + bx * 32 + x];
    __syncthreads();
    #pragma unroll
    for (int p = 0; p < 32; p += 8)
        dst[(size_t)(bx * 32 + y + p) * K + by * 32 + x] = (bf16)t[x][y + p];
}

// fp32 -> bf16 elementwise
__global__ __launch_bounds__(256) void cvt_kernel(
    const float* __restrict__ in, bf16* __restrict__ out, int n4)
{
    int i = blockIdx.x * 256 + threadIdx.x;
    if (i >= n4) return;
    float4 v = ((const float4*)in)[i];
    out[4 * i + 0] = (bf16)v.x;
    out[4 * i + 1] = (bf16)v.y;
    out[4 * i + 2] = (bf16)v.z;
    out[4 * i + 3] = (bf16)v.w;
}

// kv = x @ Wm + bm  (K=4), bf16 out.
__global__ __launch_bounds__(256) void kv_kernel(
    const float* __restrict__ x, const float* __restrict__ Wm,
    const float* __restrict__ bm, bf16* __restrict__ kv)
{
    int idx = blockIdx.x * 256 + threadIdx.x;
    int r = idx >> 10, n = idx & 1023;
    float4 xv = *(const float4*)(x + (size_t)r * 4);
    float v = bm[n] + xv.x * Wm[n] + xv.y * Wm[1024 + n]
                    + xv.z * Wm[2048 + n] + xv.w * Wm[3072 + n];
    kv[idx] = (bf16)v;
}

// 3D RoPE: bf16 in (row stride istr, col offset icoff) -> bf16 out (rows x 512).
__global__ __launch_bounds__(256) void rope_b_kernel(
    const bf16* __restrict__ in, bf16* __restrict__ out,
    int tok, int gdiv, int wdiv, int total, float sc, int istr, int icoff)
{
    int idx = blockIdx.x * 256 + threadIdx.x;
    if (idx >= total) return;
    int row = idx >> 7;
    int r2 = idx & 127;
    int h = r2 >> 5;
    int j2 = r2 & 31;
    int j = 2 * j2;
    int n = row % tok;
    int t = n / gdiv;
    int g = n % gdiv;
    int gh = g / wdiv;
    int gw = g % wdiv;
    float pa = (j < 22) ? (float)t : (j < 43) ? (float)gh : (float)gw;
    int j1 = j + 1;
    float pb = (j1 < 22) ? (float)t : (j1 < 43) ? (float)gh : (float)gw;
    float fra = pa * exp2f(-(float)j  * 0.20762050593045954f);
    float frb = pb * exp2f(-(float)j1 * 0.20762050593045954f);
    float ca = cosf(fra), sa = sinf(fra);
    float cb = cosf(frb), sb = sinf(frb);
    size_t ibase = (size_t)row * istr + icoff + (size_t)h * 128 + j;
    size_t obase = (size_t)row * 512 + (size_t)h * 128 + j;
    union { u32 w; bf16 e[2]; } ua, ub;
    ua.w = *(const u32*)(in + ibase);
    ub.w = *(const u32*)(in + ibase + 64);
    float x1a = (float)ua.e[0], x1b = (float)ua.e[1];
    float x2a = (float)ub.e[0], x2b = (float)ub.e[1];
    *(u32*)(out + obase)      = pack_bf16((x1a * ca - x2a * sa) * sc,
                                          (x1b * cb - x2b * sb) * sc);
    *(u32*)(out + obase + 64) = pack_bf16((x2a * ca + x1a * sa) * sc,
                                          (x2b * cb + x1b * sb) * sc);
}

// Coalesced V transpose: kv16[t][512 + h*128 + d] -> Vt[b][h][d][2048]
__global__ __launch_bounds__(256) void vt_tiled(
    const bf16* __restrict__ kv16, bf16* __restrict__ vt)
{
    __shared__ bf16 t[64][72];
    const int tt = blockIdx.x * 64;
    const int d0 = blockIdx.y * 64;
    const int bh = blockIdx.z;
    const int b = bh >> 2, h = bh & 3;
    const int rr = threadIdx.x >> 4;
    const int cc = (threadIdx.x & 15) * 4;
    #pragma unroll
    for (int p = 0; p < 4; ++p) {
        int r = rr + p * 16;
        *(bf16x4*)&t[r][cc] = *(const bf16x4*)
            (kv16 + (size_t)(b * ROWS_K + tt + r) * 1024 + 512 + h * 128 + d0 + cc);
    }
    __syncthreads();
    #pragma unroll
    for (int p = 0; p < 4; ++p) {
        int r = rr + p * 16;   // d-local
        bf16x4 v;
        v[0] = t[cc + 0][r]; v[1] = t[cc + 1][r];
        v[2] = t[cc + 2][r]; v[3] = t[cc + 3][r];
        *(bf16x4*)(vt + (size_t)bh * HD * ROWS_K + (size_t)(d0 + r) * ROWS_K + tt + cc) = v;
    }
}

// LayerNorm in-place on (rows x 512) + bf16 copy.
__global__ __launch_bounds__(256) void ln_kernel(
    float* __restrict__ xb, const float* __restrict__ g,
    const float* __restrict__ be, bf16* __restrict__ out16)
{
    int wave = threadIdx.x >> 6, lane = threadIdx.x & 63;
    size_t row = (size_t)blockIdx.x * 4 + wave;
    float* xp = xb + row * 512;
    float4 a = ((const float4*)xp)[lane];
    float4 b = ((const float4*)xp)[lane + 64];
    float s  = a.x + a.y + a.z + a.w + b.x + b.y + b.z + b.w;
    float sq = a.x*a.x + a.y*a.y + a.z*a.z + a.w*a.w
             + b.x*b.x + b.y*b.y + b.z*b.z + b.w*b.w;
    #pragma unroll
    for (int off = 32; off; off >>= 1) {
        s  += __shfl_xor(s, off);
        sq += __shfl_xor(sq, off);
    }
    float mean = s * (1.0f / 512.0f);
    float var  = sq * (1.0f / 512.0f) - mean * mean;
    float rstd = rsqrtf(var + 1e-5f);
    float4 gv1 = ((const float4*)g)[lane],  gv2 = ((const float4*)g)[lane + 64];
    float4 bv1 = ((const float4*)be)[lane], bv2 = ((const float4*)be)[lane + 64];
    a.x = (a.x - mean) * rstd * gv1.x + bv1.x;
    a.y = (a.y - mean) * rstd * gv1.y + bv1.y;
    a.z = (a.z - mean) * rstd * gv1.z + bv1.z;
    a.w = (a.w - mean) * rstd * gv1.w + bv1.w;
    b.x = (b.x - mean) * rstd * gv2.x + bv2.x;
    b.y = (b.y - mean) * rstd * gv2.y + bv2.y;
    b.z = (b.z - mean) * rstd * gv2.z + bv2.z;
    b.w = (b.w - mean) * rstd * gv2.w + bv2.w;
    ((float4*)xp)[lane]      = a;
    ((float4*)xp)[lane + 64] = b;
    bf16* op = out16 + row * 512;
    *(u32*)(op + lane * 4)       = pack_bf16(a.x, a.y);
    *(u32*)(op + lane * 4 + 2)   = pack_bf16(a.z, a.w);
    *(u32*)(op + 256 + lane * 4)     = pack_bf16(b.x, b.y);
    *(u32*)(op + 256 + lane * 4 + 2) = pack_bf16(b.z, b.w);
}

// ---------------------------------------------------------------------------
// MFMA flash attention, KV-split-2 (flash-decoding) partial kernel.
// Body = EXACT round-0 register structure (4 waves x 32q, single-buffered
// staging, compiled to 128 VGPR, measured 121us/392blk). Rounds 1-3 showed
// any restructure (16q/wave or +32 reg staging state) makes the allocator
// collapse/spill (56-108 VGPR, 3-5x regression) -- so per-wave code is kept
// untouched and parallelism is doubled via the KV axis instead:
//   grid 784 = 2 parts x 2b x 4h x 49 qtiles; each block does 16 KV tiles.
//   ~3 blocks/CU resident (12 waves/CU) vs round-0's 1.5 (6 waves/CU).
// Partials are written NORMALIZED (o/l, bf16, attn_b layout -> reuses the
// round-0 coalesced Osh epilogue) + per-row m,l in f32; comb_kernel merges:
// out = w1*o1 + w2*o2 with w_p = l_p*exp(m_p-max)/sum (convex -> no error
// amplification beyond bf16 rounding).
// Validated deltas kept: padded LDS strides (140/76/140: conflicts
// 11.4M->3.2M, rounds 1-3), exact defer-rescale, setprio around MFMA (m191).
// LDS: 64*140*2 + 128*76*2 = 37376 B -> 4 blocks/CU possible; grid needs 3.
// ---------------------------------------------------------------------------
#define KS 140
#define VS 76
#define OS 140

__global__ __launch_bounds__(256, 2) void mattn_kernel(
    const bf16* __restrict__ qs, const bf16* __restrict__ ks,
    const bf16* __restrict__ vt, bf16* __restrict__ op0,
    bf16* __restrict__ op1, float* __restrict__ mbuf,
    float* __restrict__ lbuf)
{
    __shared__ __align__(16) char smem[37376];
    bf16* Ksh = (bf16*)smem;            // [64][KS]
    bf16* Vsh = (bf16*)(smem + 17920);  // [128][VS]

    const int tid = threadIdx.x;
    const int wave = tid >> 6, lane = tid & 63;
    const int quad = lane >> 4, c = lane & 15;
    const int bid = blockIdx.x;
    const int qt = bid % 49;
    const int h  = (bid / 49) & 3;
    const int rest = bid / 196;         // 0..3
    const int b    = rest & 1;
    const int part = rest >> 1;

    const int q0 = qt * 128 + wave * 32;
    const bf16* qg = qs + (size_t)(b * ROWS_Q + q0) * HID + h * HD;
    const bf16* kg = ks + (size_t)(b * ROWS_K) * HID + h * HD;
    const bf16* vg = vt + (size_t)(b * NH + h) * HD * ROWS_K;

    bf16x8 qf[2][4];
    #pragma unroll
    for (int n = 0; n < 2; ++n)
        #pragma unroll
        for (int s = 0; s < 4; ++s)
            qf[n][s] = *(const bf16x8*)(qg + (size_t)(n * 16 + c) * HID + s * 32 + quad * 8);

    f32x4 o[8][2] = {};
    float m_i[2] = {-1e30f, -1e30f}, l_i[2] = {0.0f, 0.0f};

    const int st_t = tid >> 2;
    const int st_d = (tid & 3) * 32;
    const int sv_d = tid >> 1;
    const int sv_t = (tid & 1) * 32;

    const int kt0 = part * 16;
    for (int kt = kt0; kt < kt0 + 16; ++kt) {
        __syncthreads();
        {
            const bf16* src = kg + (size_t)(kt * 64 + st_t) * HID + st_d;
            bf16* dst = Ksh + st_t * KS + st_d;
            #pragma unroll
            for (int i = 0; i < 4; ++i)
                *(bf16x8*)(dst + i * 8) = *(const bf16x8*)(src + i * 8);
        }
        {
            const bf16* src = vg + (size_t)sv_d * ROWS_K + kt * 64 + sv_t;
            bf16* dst = Vsh + sv_d * VS + sv_t;
            #pragma unroll
            for (int i = 0; i < 4; ++i)
                *(bf16x8*)(dst + i * 8) = *(const bf16x8*)(src + i * 8);
        }
        __syncthreads();

        // QK^T: s[mi][n][r] = score(k = mi*16 + quad*4 + r, q = n*16 + c)
        f32x4 s[4][2] = {};
        __builtin_amdgcn_s_setprio(1);
        #pragma unroll
        for (int ksi = 0; ksi < 4; ++ksi) {
            bf16x8 kf[4];
            #pragma unroll
            for (int mi = 0; mi < 4; ++mi)
                kf[mi] = *(const bf16x8*)(Ksh + (mi * 16 + c) * KS + ksi * 32 + quad * 8);
            #pragma unroll
            for (int mi = 0; mi < 4; ++mi)
                #pragma unroll
                for (int n = 0; n < 2; ++n)
                    s[mi][n] = __builtin_amdgcn_mfma_f32_16x16x32_bf16(
                        kf[mi], qf[n][ksi], s[mi][n], 0, 0, 0);
        }
        __builtin_amdgcn_s_setprio(0);

        // online softmax
        float mx[2];
        #pragma unroll
        for (int n = 0; n < 2; ++n) {
            float m = -1e30f;
            #pragma unroll
            for (int mi = 0; mi < 4; ++mi)
                #pragma unroll
                for (int r = 0; r < 4; ++r) m = fmaxf(m, s[mi][n][r]);
            m = fmaxf(m, __shfl_xor(m, 16));
            m = fmaxf(m, __shfl_xor(m, 32));
            mx[n] = m;
        }
        if (!__all((mx[0] <= m_i[0]) && (mx[1] <= m_i[1]))) {
            #pragma unroll
            for (int n = 0; n < 2; ++n) {
                float mn = fmaxf(m_i[n], mx[n]);
                float alpha = __expf(m_i[n] - mn);
                m_i[n] = mn;
                l_i[n] *= alpha;
                #pragma unroll
                for (int md = 0; md < 8; ++md) {
                    o[md][n][0] *= alpha; o[md][n][1] *= alpha;
                    o[md][n][2] *= alpha; o[md][n][3] *= alpha;
                }
            }
        }
        #pragma unroll
        for (int n = 0; n < 2; ++n) {
            float sm = 0.0f;
            #pragma unroll
            for (int mi = 0; mi < 4; ++mi)
                #pragma unroll
                for (int r = 0; r < 4; ++r) {
                    float p = __expf(s[mi][n][r] - m_i[n]);
                    s[mi][n][r] = p;
                    sm += p;
                }
            sm += __shfl_xor(sm, 16);
            sm += __shfl_xor(sm, 32);
            l_i[n] += sm;
        }

        // repack P (rows=k, cols=q) into PV B-operand fragments
        u32 pk[4][2][2];
        #pragma unroll
        for (int mi = 0; mi < 4; ++mi)
            #pragma unroll
            for (int n = 0; n < 2; ++n) {
                pk[mi][n][0] = pack_bf16(s[mi][n][0], s[mi][n][1]);
                pk[mi][n][1] = pack_bf16(s[mi][n][2], s[mi][n][3]);
            }
        bf16x8 pf[2][2];
        #pragma unroll
        for (int kst = 0; kst < 2; ++kst)
            #pragma unroll
            for (int n = 0; n < 2; ++n) {
                union { bf16x8 v8; u32 d[4]; } u;
                #pragma unroll
                for (int dw = 0; dw < 4; ++dw) {
                    int srcl = ((quad & 1) * 2 + (dw >> 1)) * 16 + c;
                    u32 lo = (u32)__shfl((int)pk[2 * kst][n][dw & 1], srcl);
                    u32 hi = (u32)__shfl((int)pk[2 * kst + 1][n][dw & 1], srcl);
                    u.d[dw] = (quad >= 2) ? hi : lo;
                }
                pf[kst][n] = u.v8;
            }

        // PV: o[md][n][r] = O(q=n*16+c, d = md*16 + quad*4 + r)
        __builtin_amdgcn_s_setprio(1);
        #pragma unroll
        for (int kst = 0; kst < 2; ++kst)
            #pragma unroll
            for (int md = 0; md < 8; ++md) {
                bf16x8 vf = *(const bf16x8*)(Vsh + (md * 16 + c) * VS + kst * 32 + quad * 8);
                #pragma unroll
                for (int n = 0; n < 2; ++n)
                    o[md][n] = __builtin_amdgcn_mfma_f32_16x16x32_bf16(
                        vf, pf[kst][n], o[md][n], 0, 0, 0);
            }
        __builtin_amdgcn_s_setprio(0);
    }

    // per-row m,l for the combine
    if (quad == 0) {
        #pragma unroll
        for (int n = 0; n < 2; ++n) {
            int row = b * ROWS_Q + q0 + n * 16 + c;
            mbuf[(part * 4 + h) * MQ + row] = m_i[n];
            lbuf[(part * 4 + h) * MQ + row] = l_i[n];
        }
    }

    __syncthreads();
    bf16* Osh = (bf16*)smem + wave * (32 * OS);
    float inv[2] = {1.0f / l_i[0], 1.0f / l_i[1]};
    #pragma unroll
    for (int md = 0; md < 8; ++md)
        #pragma unroll
        for (int n = 0; n < 2; ++n)
            #pragma unroll
            for (int hh = 0; hh < 2; ++hh) {
                u32 w = pack_bf16(o[md][n][2 * hh] * inv[n], o[md][n][2 * hh + 1] * inv[n]);
                int d = md * 16 + quad * 4 + 2 * hh;
                int qq = n * 16 + c;
                *(u32*)(Osh + qq * OS + d) = w;
            }
    __syncthreads();
    bf16* opb = part ? op1 : op0;
    bf16* og = opb + (size_t)(b * ROWS_Q + q0) * HID + h * HD;
    #pragma unroll
    for (int i = 0; i < 8; ++i) {
        int idx = i * 64 + lane;
        int qq = idx >> 4;
        int ch = idx & 15;
        bf16x8 vv = *(const bf16x8*)(Osh + qq * OS + ch * 8);
        *(bf16x8*)(og + (size_t)qq * HID + ch * 8) = vv;
    }
}

// Combine the two normalized KV-half partials: out = w1*o1 + w2*o2.
__global__ __launch_bounds__(256) void comb_kernel(
    const bf16* __restrict__ o0, const bf16* __restrict__ o1,
    const float* __restrict__ mbuf, const float* __restrict__ lbuf,
    bf16* __restrict__ outb)
{
    int idx = blockIdx.x * 256 + threadIdx.x;   // MQ*64 groups of 8 bf16
    int row = idx >> 6;
    int col8 = idx & 63;
    int h = col8 >> 4;
    int mli = h * MQ + row;
    float m1 = mbuf[mli],          l1 = lbuf[mli];
    float m2 = mbuf[4 * MQ + mli], l2 = lbuf[4 * MQ + mli];
    float mm = fmaxf(m1, m2);
    float a1 = l1 * __expf(m1 - mm), a2 = l2 * __expf(m2 - mm);
    float inv = 1.0f / (a1 + a2);
    float w1 = a1 * inv, w2 = a2 * inv;
    size_t off = (size_t)idx * 8;
    bf16x8 v1 = *(const bf16x8*)(o0 + off);
    bf16x8 v2 = *(const bf16x8*)(o1 + off);
    bf16x8 r;
    #pragma unroll
    for (int j = 0; j < 8; ++j)
        r[j] = (bf16)((float)v1[j] * w1 + (float)v2[j] * w2);
    *(bf16x8*)(outb + off) = r;
}

extern "C" void kernel_launch(void* const* d_in, const int* in_sizes, int n_in,
                              void* d_out, int out_size, void* d_ws, size_t ws_size,
                              hipStream_t stream)
{
    const float* x     = (const float*)d_in[0];
    const float* slow  = (const float*)d_in[1];
    const float* Wq_in = (const float*)d_in[3];
    const float* bq_in = (const float*)d_in[4];
    const float* Wm    = (const float*)d_in[5];
    const float* bm    = (const float*)d_in[6];
    const float* Wq    = (const float*)d_in[7];
    const float* bq    = (const float*)d_in[8];
    const float* Wk    = (const float*)d_in[9];
    const float* bk    = (const float*)d_in[10];
    const float* Wv    = (const float*)d_in[11];
    const float* bv    = (const float*)d_in[12];
    const float* Wo    = (const float*)d_in[13];
    const float* bo    = (const float*)d_in[14];
    const float* g1    = (const float*)d_in[15];
    const float* be1   = (const float*)d_in[16];
    const float* W1    = (const float*)d_in[17];
    const float* b1    = (const float*)d_in[18];
    const float* W2    = (const float*)d_in[19];
    const float* b2    = (const float*)d_in[20];
    const float* g2    = (const float*)d_in[21];
    const float* be2   = (const float*)d_in[22];
    const float* M1    = (const float*)d_in[23];
    const float* bm1   = (const float*)d_in[24];
    const float* M2    = (const float*)d_in[25];
    const float* bm2   = (const float*)d_in[26];
    float* out = (float*)d_out;

    // ---- workspace layout ----
    float* q_in_f = (float*)d_ws;                         // MQ*512 f32
    float* ob     = q_in_f + (size_t)MQ * HID;            // MQ*512 f32
    float* bkv    = ob + (size_t)MQ * HID;                // 1024 f32
    bf16* shared_b = (bf16*)(bkv + 1024);                 // MQ*1024 (slow_b/attn_b/ff1_b/m1_b)
    bf16* q_in_b = shared_b + (size_t)MQ * FF;            // MQ*512
    bf16* kv_b   = q_in_b + (size_t)MQ * HID;             // MK*1024
    bf16* h_b    = kv_b + (size_t)MK * EMB;               // MQ*512
    bf16* q16    = h_b + (size_t)MQ * HID;                // MQ*512
    bf16* kv16   = q16 + (size_t)MQ * HID;                // MK*1024 (k|v fused)
    bf16* qbt    = kv16 + (size_t)MK * EMB;               // MQ*512
    bf16* kbt    = qbt + (size_t)MQ * HID;                // MK*512
    bf16* Vt     = kbt + (size_t)MK * HID;                // 8*128*2048
    bf16* Wq_in_t = Vt + (size_t)8 * HD * ROWS_K;         // 512*896
    bf16* Wq_t  = Wq_in_t + 512 * 896;                    // 512*512
    bf16* kvw_t = Wq_t + 512 * 512;                       // 1024*1024 (Wk_t | Wv_t)
    bf16* Wo_t  = kvw_t + 1024 * 1024;                    // 512*512
    bf16* W1_t  = Wo_t + 512 * 512;                       // 1024*512
    bf16* W2_t  = W1_t + 1024 * 512;                      // 512*1024
    bf16* M1_t  = W2_t + 512 * 1024;                      // 1024*512
    bf16* M2_t  = M1_t + 1024 * 512;                      // 896*1024
    bf16* slow_b = shared_b;
    bf16* attn_b = shared_b;
    bf16* ff1_b  = shared_b;
    bf16* m1_b   = shared_b;

    // attention partial buffers: reuse regions dead by the time mattn runs
    bf16* opart0 = q16;               // dead after rope(q16 -> qbt)
    bf16* opart1 = q_in_b;            // dead after q-projection GEMM
    float* mlm   = (float*)kv16;      // dead after rope(k) + vt_tiled; 8*MQ f32
    float* mll   = mlm + 8 * MQ;      //                                8*MQ f32

    dim3 blk(256);

    // ---- all weight transposes in one launch ----
    TDescs td;
    int t0 = 0;
    auto set = [&](int i, const float* s, bf16* d, int K, int N) {
        td.d[i] = {s, d, K, N, t0};
        t0 += (N / 32) * (K / 32);
    };
    set(0, Wq_in, Wq_in_t, 896, 512);
    set(1, Wq,    Wq_t,    512, 512);
    set(2, Wk,    kvw_t,              1024, 512);
    set(3, Wv,    kvw_t + 512 * 1024, 1024, 512);
    set(4, Wo,    Wo_t,    512, 512);
    set(5, W1,    W1_t,    512, 1024);
    set(6, W2,    W2_t,    1024, 512);
    set(7, M1,    M1_t,    512, 1024);
    set(8, M2,    M2_t,    1024, 896);
    transpose_all<<<t0, blk, 0, stream>>>(td);

    // bias concat for fused KV GEMM
    hipMemcpyAsync(bkv,       bk, 512 * sizeof(float), hipMemcpyDeviceToDevice, stream);
    hipMemcpyAsync(bkv + 512, bv, 512 * sizeof(float), hipMemcpyDeviceToDevice, stream);

    cvt_kernel<<<(MQ * DQ / 4 + 255) / 256, blk, 0, stream>>>(slow, slow_b, MQ * DQ / 4);
    kv_kernel<<<(MK * EMB) / 256, blk, 0, stream>>>(x, Wm, bm, kv_b);

    // q_in = slow @ Wq_in + bq_in -> fp32 (residual) + bf16   grid 4x196
    mgemm64<OP_BIAS, true, true><<<dim3(4, 196), blk, 0, stream>>>(
        slow_b, Wq_in_t, bq_in, nullptr, q_in_f, q_in_b, MQ, HID, DQ);
    // q projection -> bf16   grid 4x196
    mgemm64<OP_BIAS, false, true><<<dim3(4, 196), blk, 0, stream>>>(
        q_in_b, Wq_t, bq, nullptr, nullptr, q16, MQ, HID, HID);
    // fused k|v projection -> kv16 (MK x 1024)   grid 8x64
    mgemm64<OP_BIAS, false, true><<<dim3(8, 64), blk, 0, stream>>>(
        kv_b, kvw_t, bkv, nullptr, nullptr, kv16, MK, 1024, EMB);
    // RoPE (q pre-scaled by 1/sqrt(128)); k read from fused kv16
    rope_b_kernel<<<(MQ * 128 + 255) / 256, blk, 0, stream>>>(
        q16, qbt, ROWS_Q, 196, 14, MQ * 128, 0.08838834764831843f, 512, 0);
    rope_b_kernel<<<(MK * 128 + 255) / 256, blk, 0, stream>>>(
        kv16, kbt, ROWS_K, 64, 8, MK * 128, 1.0f, 1024, 0);
    // V transpose (coalesced)
    vt_tiled<<<dim3(32, 2, 8), blk, 0, stream>>>(kv16, Vt);
    // MFMA flash attention, KV-split-2: grid 784 partials + combine
    mattn_kernel<<<dim3(784), blk, 0, stream>>>(qbt, kbt, Vt, opart0, opart1, mlm, mll);
    comb_kernel<<<dim3(MQ * 64 / 256), blk, 0, stream>>>(opart0, opart1, mlm, mll, attn_b);
    // pre_ln = attn @ Wo + bo + q_in   grid 4x196
    mgemm64<OP_RES, true, false><<<dim3(4, 196), blk, 0, stream>>>(
        attn_b, Wo_t, bo, q_in_f, ob, nullptr, MQ, HID, HID);
    ln_kernel<<<MQ / 4, blk, 0, stream>>>(ob, g1, be1, h_b);
    // ff1 = gelu(h @ W1 + b1)   grid 8x98 (128-tile)
    mgemm<OP_GELU, false, true><<<dim3(8, 98), blk, 0, stream>>>(
        h_b, W1_t, b1, nullptr, nullptr, ff1_b, MQ, FF, HID);
    // pre2 = ff1 @ W2 + b2 + h   grid 4x196
    mgemm64<OP_RES, true, false><<<dim3(4, 196), blk, 0, stream>>>(
        ff1_b, W2_t, b2, ob, q_in_f, nullptr, MQ, HID, FF);
    ln_kernel<<<MQ / 4, blk, 0, stream>>>(q_in_f, g2, be2, h_b);
    // m1 = gelu(h2 @ M1 + bm1)   grid 8x98
    mgemm<OP_GELU, false, true><<<dim3(8, 98), blk, 0, stream>>>(
        h_b, M1_t, bm1, nullptr, nullptr, m1_b, MQ, 2 * HID, HID);
    // out = m1 @ M2 + bm2   grid 7x98
    mgemm<OP_BIAS, true, false><<<dim3(7, 98), blk, 0, stream>>>(
        m1_b, M2_t, bm2, nullptr, out, nullptr, MQ, OUTD, 2 * HID);
}